// Round 1
// baseline (8680.454 us; speedup 1.0000x reference)
//
#include <hip/hip_runtime.h>

#define NN 100000
#define EE 1600000
#define GG 512
#define LL 5
#define HID 64
#define RCOLS (HID*LL)   // 320
#define OUTC 16

// ---------------- scatter-add aggregation ----------------
template<int CH>
__global__ __launch_bounds__(256) void scatter_kernel(
    const float* __restrict__ h,
    const int* __restrict__ src, const int* __restrict__ dst,
    float* __restrict__ agg)
{
    constexpr int PER = CH / 4;           // float4 groups per edge
    constexpr int SH  = (CH == 128) ? 5 : 4;
    constexpr int MSK = PER - 1;
    const int total = EE * PER;
    for (int i = blockIdx.x * 256 + threadIdx.x; i < total; i += gridDim.x * 256) {
        int e  = i >> SH;
        int cg = (i & MSK) << 2;
        int s = src[e], d = dst[e];
        float4 v = *(const float4*)(h + (size_t)s * CH + cg);
        float* p = agg + (size_t)d * CH + cg;
        unsafeAtomicAdd(p + 0, v.x);
        unsafeAtomicAdd(p + 1, v.y);
        unsafeAtomicAdd(p + 2, v.z);
        unsafeAtomicAdd(p + 3, v.w);
    }
}

// ---------------- fused MLP: z=(1+eps)h+agg; z@W1+b1; BN;ReLU; @W2+b2; BN;ReLU; pool ----------------
template<int K>
__global__ __launch_bounds__(256) void mlp_kernel(
    const float* __restrict__ h_in,    // [N,K]
    const float* __restrict__ agg,     // [N,K]
    const float* __restrict__ eps_arr, int l,
    const float* __restrict__ W1, const float* __restrict__ b1,   // [K,64],[64]
    const float* __restrict__ W2, const float* __restrict__ b2,   // [64,64],[64]
    const float* __restrict__ g_a, const float* __restrict__ be_a,
    const float* __restrict__ m_a, const float* __restrict__ v_a,
    const float* __restrict__ g_b, const float* __restrict__ be_b,
    const float* __restrict__ m_b, const float* __restrict__ v_b,
    const int* __restrict__ batch,
    float* __restrict__ h_out,         // [N,64]
    float* __restrict__ readout,       // [G,320]
    int layer_off)
{
    __shared__ float W1s[K * 64];
    __shared__ float W2s[64 * 64];
    __shared__ float zs[4][K];

    for (int i = threadIdx.x; i < K * 64 / 4; i += 256)
        ((float4*)W1s)[i] = ((const float4*)W1)[i];
    for (int i = threadIdx.x; i < 64 * 64 / 4; i += 256)
        ((float4*)W2s)[i] = ((const float4*)W2)[i];

    const int lane = threadIdx.x & 63;
    const int wave = threadIdx.x >> 6;
    const float eps_l = 1.0f + eps_arr[l];
    // fold BN into scale/shift (per output channel = lane)
    const float sa  = g_a[lane] * rsqrtf(v_a[lane] + 1e-5f);
    const float sha = be_a[lane] - m_a[lane] * sa;
    const float sb  = g_b[lane] * rsqrtf(v_b[lane] + 1e-5f);
    const float shb = be_b[lane] - m_b[lane] * sb;
    const float bias1 = b1[lane];
    const float bias2 = b2[lane];
    __syncthreads();

    const int ngroups = (NN + 3) >> 2;
    for (int grp = blockIdx.x; grp < ngroups; grp += gridDim.x) {
        const int row = grp * 4 + wave;
        if (row < NN) {
            const float* hr = h_in + (size_t)row * K;
            const float* ar = agg  + (size_t)row * K;
            #pragma unroll
            for (int k = lane; k < K; k += 64)
                zs[wave][k] = eps_l * hr[k] + ar[k];
            // wave-private LDS row: LDS ops are in-order per wave, no barrier needed

            float a0 = 0.f, a1 = 0.f, a2 = 0.f, a3 = 0.f;
            #pragma unroll
            for (int k = 0; k < K; k += 4) {
                a0 += zs[wave][k + 0] * W1s[(k + 0) * 64 + lane];
                a1 += zs[wave][k + 1] * W1s[(k + 1) * 64 + lane];
                a2 += zs[wave][k + 2] * W1s[(k + 2) * 64 + lane];
                a3 += zs[wave][k + 3] * W1s[(k + 3) * 64 + lane];
            }
            float z1 = bias1 + ((a0 + a1) + (a2 + a3));
            float v1 = fmaxf(z1 * sa + sha, 0.0f);

            zs[wave][lane] = v1;   // reuse row buffer for hidden vector

            float c0 = 0.f, c1 = 0.f, c2 = 0.f, c3 = 0.f;
            #pragma unroll
            for (int k = 0; k < 64; k += 4) {
                c0 += zs[wave][k + 0] * W2s[(k + 0) * 64 + lane];
                c1 += zs[wave][k + 1] * W2s[(k + 1) * 64 + lane];
                c2 += zs[wave][k + 2] * W2s[(k + 2) * 64 + lane];
                c3 += zs[wave][k + 3] * W2s[(k + 3) * 64 + lane];
            }
            float z2 = bias2 + ((c0 + c1) + (c2 + c3));
            float v2 = fmaxf(z2 * sb + shb, 0.0f);

            h_out[(size_t)row * 64 + lane] = v2;
            const int g = batch[row];
            unsafeAtomicAdd(readout + (size_t)g * RCOLS + layer_off + lane, v2);
        }
    }
}

// ---------------- final graph-level GEMM: [G,320] @ [320,16] + bc ----------------
__global__ __launch_bounds__(256) void final_gemm(
    const float* __restrict__ R, const float* __restrict__ Wc,
    const float* __restrict__ bc, float* __restrict__ out)
{
    const int tid = blockIdx.x * 256 + threadIdx.x;
    if (tid >= GG * OUTC) return;
    const int g = tid >> 4;
    const int o = tid & 15;
    float acc = bc[o];
    const float* r = R + (size_t)g * RCOLS;
    #pragma unroll 8
    for (int k = 0; k < RCOLS; ++k)
        acc += r[k] * Wc[k * OUTC + o];
    out[tid] = acc;
}

extern "C" void kernel_launch(void* const* d_in, const int* in_sizes, int n_in,
                              void* d_out, int out_size, void* d_ws, size_t ws_size,
                              hipStream_t stream)
{
    const float* x    = (const float*)d_in[0];
    const int*   ei   = (const int*)d_in[1];
    const int*   batch= (const int*)d_in[2];
    const float* eps  = (const float*)d_in[3];
    const float* W1_0 = (const float*)d_in[4];
    const float* b1_0 = (const float*)d_in[5];
    const float* W1_r = (const float*)d_in[6];
    const float* b1_r = (const float*)d_in[7];
    const float* g_a  = (const float*)d_in[8];
    const float* be_a = (const float*)d_in[9];
    const float* m_a  = (const float*)d_in[10];
    const float* v_a  = (const float*)d_in[11];
    const float* W2   = (const float*)d_in[12];
    const float* b2   = (const float*)d_in[13];
    const float* g_b  = (const float*)d_in[14];
    const float* be_b = (const float*)d_in[15];
    const float* m_b  = (const float*)d_in[16];
    const float* v_b  = (const float*)d_in[17];
    const float* Wc   = (const float*)d_in[18];
    const float* bc   = (const float*)d_in[19];
    float* out = (float*)d_out;

    const int* src = ei;
    const int* dst = ei + EE;

    // workspace layout (bytes, 256-aligned)
    char* ws = (char*)d_ws;
    float* agg     = (float*)(ws);                              // N*128*4 = 51.2e6
    float* h_a     = (float*)(ws + 51200000);                   // N*64*4  = 25.6e6
    float* h_b     = (float*)(ws + 76800000);                   // N*64*4
    float* readout = (float*)(ws + 102400000);                  // G*320*4 = 655360

    hipMemsetAsync(readout, 0, (size_t)GG * RCOLS * 4, stream);

    float* h_cur = h_a;
    float* h_nxt = h_b;

    for (int l = 0; l < LL; ++l) {
        const int CH = (l == 0) ? 128 : 64;
        hipMemsetAsync(agg, 0, (size_t)NN * CH * 4, stream);
        const float* hin = (l == 0) ? x : h_cur;
        if (l == 0)
            scatter_kernel<128><<<4096, 256, 0, stream>>>(hin, src, dst, agg);
        else
            scatter_kernel<64><<<4096, 256, 0, stream>>>(hin, src, dst, agg);

        const float* W1 = (l == 0) ? W1_0 : (W1_r + (size_t)(l - 1) * 64 * 64);
        const float* b1 = (l == 0) ? b1_0 : (b1_r + (size_t)(l - 1) * 64);
        const int off = l * 64;
        if (l == 0) {
            mlp_kernel<128><<<2048, 256, 0, stream>>>(
                hin, agg, eps, l, W1, b1,
                W2 + (size_t)l * 64 * 64, b2 + off,
                g_a + off, be_a + off, m_a + off, v_a + off,
                g_b + off, be_b + off, m_b + off, v_b + off,
                batch, h_nxt, readout, off);
        } else {
            mlp_kernel<64><<<2048, 256, 0, stream>>>(
                hin, agg, eps, l, W1, b1,
                W2 + (size_t)l * 64 * 64, b2 + off,
                g_a + off, be_a + off, m_a + off, v_a + off,
                g_b + off, be_b + off, m_b + off, v_b + off,
                batch, h_nxt, readout, off);
        }
        // swap
        float* t = h_cur; h_cur = h_nxt; h_nxt = t;
    }

    final_gemm<<<(GG * OUTC + 255) / 256, 256, 0, stream>>>(readout, Wc, bc, out);
}

// Round 2
// 1561.322 us; speedup vs baseline: 5.5597x; 5.5597x over previous
//
#include <hip/hip_runtime.h>

#define NN 100000
#define EE 1600000
#define GG 512
#define LL 5
#define HID 64
#define RCOLS (HID*LL)   // 320
#define OUTC 16

// ---------------- CSR build: histogram -> scan -> fill ----------------
__global__ __launch_bounds__(256) void hist_kernel(
    const int* __restrict__ dst, int* __restrict__ deg)
{
    for (int e = blockIdx.x * 256 + threadIdx.x; e < EE; e += gridDim.x * 256)
        atomicAdd(&deg[dst[e]], 1);
}

__global__ __launch_bounds__(1024) void scan_kernel(
    const int* __restrict__ deg, int* __restrict__ rowptr, int* __restrict__ cursor)
{
    __shared__ int sums[1024];
    const int t = threadIdx.x;
    const int chunk = (NN + 1023) / 1024;     // 98
    const int lo = t * chunk;
    const int hi = (lo + chunk < NN) ? lo + chunk : NN;
    int s = 0;
    for (int i = lo; i < hi; ++i) s += deg[i];
    sums[t] = s;
    __syncthreads();
    int val = s;
    for (int off = 1; off < 1024; off <<= 1) {
        int other = (t >= off) ? sums[t - off] : 0;
        __syncthreads();
        val += other;
        sums[t] = val;
        __syncthreads();
    }
    int run = val - s;                        // exclusive base for this chunk
    for (int i = lo; i < hi; ++i) {
        int d = deg[i];
        rowptr[i] = run;
        cursor[i] = run;
        run += d;
    }
    if (t == 1023) rowptr[NN] = run;          // == EE
}

__global__ __launch_bounds__(256) void fill_kernel(
    const int* __restrict__ src, const int* __restrict__ dst,
    int* __restrict__ cursor, int* __restrict__ col)
{
    for (int e = blockIdx.x * 256 + threadIdx.x; e < EE; e += gridDim.x * 256) {
        int d = dst[e];
        int p = atomicAdd(&cursor[d], 1);
        col[p] = src[e];
    }
}

// ------- fused layer: CSR gather + (1+eps)h+agg + Lin/BN/ReLU/Lin/BN/ReLU + pool -------
template<int K, bool LAST>
__global__ __launch_bounds__(256) void gin_layer_kernel(
    const float* __restrict__ h_in,    // [N,K]
    const int* __restrict__ rowptr, const int* __restrict__ col,
    const float* __restrict__ eps_arr, int l,
    const float* __restrict__ W1, const float* __restrict__ b1,   // [K,64],[64]
    const float* __restrict__ W2, const float* __restrict__ b2,   // [64,64],[64]
    const float* __restrict__ g_a, const float* __restrict__ be_a,
    const float* __restrict__ m_a, const float* __restrict__ v_a,
    const float* __restrict__ g_b, const float* __restrict__ be_b,
    const float* __restrict__ m_b, const float* __restrict__ v_b,
    const int* __restrict__ batch,
    float* __restrict__ h_out,         // [N,64]
    float* __restrict__ readout,       // [G,320]
    int layer_off)
{
    __shared__ float W1s[K * 64];
    __shared__ float W2s[64 * 64];
    __shared__ float zs[4][K];

    for (int i = threadIdx.x; i < K * 64 / 4; i += 256)
        ((float4*)W1s)[i] = ((const float4*)W1)[i];
    for (int i = threadIdx.x; i < 64 * 64 / 4; i += 256)
        ((float4*)W2s)[i] = ((const float4*)W2)[i];

    const int lane = threadIdx.x & 63;
    const int wave = threadIdx.x >> 6;
    const float eps_l = 1.0f + eps_arr[l];
    const float sa  = g_a[lane] * rsqrtf(v_a[lane] + 1e-5f);
    const float sha = be_a[lane] - m_a[lane] * sa;
    const float sb  = g_b[lane] * rsqrtf(v_b[lane] + 1e-5f);
    const float shb = be_b[lane] - m_b[lane] * sb;
    const float bias1 = b1[lane];
    const float bias2 = b2[lane];
    __syncthreads();

    const int ngroups = (NN + 3) >> 2;
    for (int grp = blockIdx.x; grp < ngroups; grp += gridDim.x) {
        const int row = grp * 4 + wave;
        if (row < NN) {
            // ---- CSR gather: agg = sum_{s in in(row)} h_in[s] ----
            const int rs = rowptr[row];
            const int re = rowptr[row + 1];
            float acc0 = 0.f, acc1 = 0.f;
            for (int j = rs; j < re; j += 64) {
                const int cnt = (re - j < 64) ? (re - j) : 64;
                int cidx = 0;
                if (lane < cnt) cidx = col[j + lane];
                for (int t = 0; t < cnt; ++t) {
                    const int s = __shfl(cidx, t, 64);
                    const float* hs = h_in + (size_t)s * K;
                    acc0 += hs[lane];
                    if (K == 128) acc1 += hs[64 + lane];
                }
            }
            const float* hr = h_in + (size_t)row * K;
            zs[wave][lane] = eps_l * hr[lane] + acc0;
            if (K == 128) zs[wave][64 + lane] = eps_l * hr[64 + lane] + acc1;
            // wave-private LDS row; per-wave LDS ops are in-order -> no barrier

            float a0 = 0.f, a1 = 0.f, a2 = 0.f, a3 = 0.f;
            #pragma unroll
            for (int k = 0; k < K; k += 4) {
                a0 += zs[wave][k + 0] * W1s[(k + 0) * 64 + lane];
                a1 += zs[wave][k + 1] * W1s[(k + 1) * 64 + lane];
                a2 += zs[wave][k + 2] * W1s[(k + 2) * 64 + lane];
                a3 += zs[wave][k + 3] * W1s[(k + 3) * 64 + lane];
            }
            float z1 = bias1 + ((a0 + a1) + (a2 + a3));
            float v1 = fmaxf(z1 * sa + sha, 0.0f);

            zs[wave][lane] = v1;

            float c0 = 0.f, c1 = 0.f, c2 = 0.f, c3 = 0.f;
            #pragma unroll
            for (int k = 0; k < 64; k += 4) {
                c0 += zs[wave][k + 0] * W2s[(k + 0) * 64 + lane];
                c1 += zs[wave][k + 1] * W2s[(k + 1) * 64 + lane];
                c2 += zs[wave][k + 2] * W2s[(k + 2) * 64 + lane];
                c3 += zs[wave][k + 3] * W2s[(k + 3) * 64 + lane];
            }
            float z2 = bias2 + ((c0 + c1) + (c2 + c3));
            float v2 = fmaxf(z2 * sb + shb, 0.0f);

            if (!LAST) h_out[(size_t)row * 64 + lane] = v2;
            const int g = batch[row];
            unsafeAtomicAdd(readout + (size_t)g * RCOLS + layer_off + lane, v2);
        }
    }
}

// ---------------- final graph-level GEMM: [G,320] @ [320,16] + bc ----------------
__global__ __launch_bounds__(256) void final_gemm(
    const float* __restrict__ R, const float* __restrict__ Wc,
    const float* __restrict__ bc, float* __restrict__ out)
{
    const int tid = blockIdx.x * 256 + threadIdx.x;
    if (tid >= GG * OUTC) return;
    const int g = tid >> 4;
    const int o = tid & 15;
    float acc = bc[o];
    const float* r = R + (size_t)g * RCOLS;
    #pragma unroll 8
    for (int k = 0; k < RCOLS; ++k)
        acc += r[k] * Wc[k * OUTC + o];
    out[tid] = acc;
}

extern "C" void kernel_launch(void* const* d_in, const int* in_sizes, int n_in,
                              void* d_out, int out_size, void* d_ws, size_t ws_size,
                              hipStream_t stream)
{
    const float* x    = (const float*)d_in[0];
    const int*   ei   = (const int*)d_in[1];
    const int*   batch= (const int*)d_in[2];
    const float* eps  = (const float*)d_in[3];
    const float* W1_0 = (const float*)d_in[4];
    const float* b1_0 = (const float*)d_in[5];
    const float* W1_r = (const float*)d_in[6];
    const float* b1_r = (const float*)d_in[7];
    const float* g_a  = (const float*)d_in[8];
    const float* be_a = (const float*)d_in[9];
    const float* m_a  = (const float*)d_in[10];
    const float* v_a  = (const float*)d_in[11];
    const float* W2   = (const float*)d_in[12];
    const float* b2   = (const float*)d_in[13];
    const float* g_b  = (const float*)d_in[14];
    const float* be_b = (const float*)d_in[15];
    const float* m_b  = (const float*)d_in[16];
    const float* v_b  = (const float*)d_in[17];
    const float* Wc   = (const float*)d_in[18];
    const float* bc   = (const float*)d_in[19];
    float* out = (float*)d_out;

    const int* src = ei;
    const int* dst = ei + EE;

    // workspace layout (bytes)
    char* ws = (char*)d_ws;
    int*   rowptr  = (int*)(ws);                         // (N+1)*4 ~ 400KB
    int*   deg     = (int*)(ws + 524288);                // 400KB
    int*   cursor  = (int*)(ws + 1048576);               // 400KB
    int*   col     = (int*)(ws + 1572864);               // E*4 = 6.4MB
    float* h_a     = (float*)(ws + 8388608);             // N*64*4 = 25.6MB
    float* h_b     = (float*)(ws + 8388608 + 25600000);  // 25.6MB
    float* readout = (float*)(ws + 8388608 + 51200000);  // G*320*4 = 640KB

    hipMemsetAsync(deg, 0, (size_t)NN * 4, stream);
    hipMemsetAsync(readout, 0, (size_t)GG * RCOLS * 4, stream);

    hist_kernel<<<2048, 256, 0, stream>>>(dst, deg);
    scan_kernel<<<1, 1024, 0, stream>>>(deg, rowptr, cursor);
    fill_kernel<<<2048, 256, 0, stream>>>(src, dst, cursor, col);

    float* h_cur = h_a;
    float* h_nxt = h_b;

    for (int l = 0; l < LL; ++l) {
        const float* hin = (l == 0) ? x : h_cur;
        const float* W1 = (l == 0) ? W1_0 : (W1_r + (size_t)(l - 1) * 64 * 64);
        const float* b1 = (l == 0) ? b1_0 : (b1_r + (size_t)(l - 1) * 64);
        const int off = l * 64;
        if (l == 0) {
            gin_layer_kernel<128, false><<<2048, 256, 0, stream>>>(
                hin, rowptr, col, eps, l, W1, b1,
                W2 + (size_t)l * 64 * 64, b2 + off,
                g_a + off, be_a + off, m_a + off, v_a + off,
                g_b + off, be_b + off, m_b + off, v_b + off,
                batch, h_nxt, readout, off);
        } else if (l < LL - 1) {
            gin_layer_kernel<64, false><<<2048, 256, 0, stream>>>(
                hin, rowptr, col, eps, l, W1, b1,
                W2 + (size_t)l * 64 * 64, b2 + off,
                g_a + off, be_a + off, m_a + off, v_a + off,
                g_b + off, be_b + off, m_b + off, v_b + off,
                batch, h_nxt, readout, off);
        } else {
            gin_layer_kernel<64, true><<<2048, 256, 0, stream>>>(
                hin, rowptr, col, eps, l, W1, b1,
                W2 + (size_t)l * 64 * 64, b2 + off,
                g_a + off, be_a + off, m_a + off, v_a + off,
                g_b + off, be_b + off, m_b + off, v_b + off,
                batch, h_nxt, readout, off);
        }
        float* t = h_cur; h_cur = h_nxt; h_nxt = t;
    }

    final_gemm<<<(GG * OUTC + 255) / 256, 256, 0, stream>>>(readout, Wc, bc, out);
}

// Round 3
// 1022.489 us; speedup vs baseline: 8.4895x; 1.5270x over previous
//
#include <hip/hip_runtime.h>

#define NN 100000
#define EE 1600000
#define GG 512
#define LL 5
#define HID 64
#define RCOLS (HID*LL)   // 320
#define OUTC 16

typedef unsigned int uint;
typedef unsigned short ushort;

__device__ __forceinline__ float bf2f(ushort u) {
    return __uint_as_float(((uint)u) << 16);
}
__device__ __forceinline__ ushort f2bf(float f) {
    uint u = __float_as_uint(f);
    u = (u + 0x7fffu + ((u >> 16) & 1u)) >> 16;   // round-to-nearest-even
    return (ushort)u;
}
__device__ __forceinline__ uint pack2(float a, float b) {
    return (uint)f2bf(a) | ((uint)f2bf(b) << 16);
}
__device__ __forceinline__ float lo16(uint p) { return __uint_as_float(p << 16); }
__device__ __forceinline__ float hi16(uint p) { return __uint_as_float(p & 0xffff0000u); }

// ---------------- CSR build: histogram -> scan -> fill ----------------
__global__ __launch_bounds__(256) void hist_kernel(
    const int* __restrict__ dst, int* __restrict__ deg)
{
    for (int e = blockIdx.x * 256 + threadIdx.x; e < EE; e += gridDim.x * 256)
        atomicAdd(&deg[dst[e]], 1);
}

__global__ __launch_bounds__(1024) void scan_kernel(
    const int* __restrict__ deg, int* __restrict__ rowptr, int* __restrict__ cursor)
{
    __shared__ int sums[1024];
    const int t = threadIdx.x;
    const int chunk = (NN + 1023) / 1024;
    const int lo = t * chunk;
    const int hi = (lo + chunk < NN) ? lo + chunk : NN;
    int s = 0;
    for (int i = lo; i < hi; ++i) s += deg[i];
    sums[t] = s;
    __syncthreads();
    int val = s;
    for (int off = 1; off < 1024; off <<= 1) {
        int other = (t >= off) ? sums[t - off] : 0;
        __syncthreads();
        val += other;
        sums[t] = val;
        __syncthreads();
    }
    int run = val - s;
    for (int i = lo; i < hi; ++i) {
        int d = deg[i];
        rowptr[i] = run;
        cursor[i] = run;
        run += d;
    }
    if (t == 1023) rowptr[NN] = run;
}

__global__ __launch_bounds__(256) void fill_kernel(
    const int* __restrict__ src, const int* __restrict__ dst,
    int* __restrict__ cursor, int* __restrict__ col)
{
    for (int e = blockIdx.x * 256 + threadIdx.x; e < EE; e += gridDim.x * 256) {
        int d = dst[e];
        int p = atomicAdd(&cursor[d], 1);
        col[p] = src[e];
    }
}

// ---------------- x (fp32 [N,128]) -> bf16-pair-packed [N,64] uints ----------------
__global__ __launch_bounds__(256) void cvt_x_kernel(
    const float* __restrict__ x, uint* __restrict__ xb)
{
    for (int i = blockIdx.x * 256 + threadIdx.x; i < NN * 64; i += gridDim.x * 256) {
        float2 v = ((const float2*)x)[i];
        xb[i] = pack2(v.x, v.y);
    }
}

// ------- fused layer: CSR gather(bf16) + (1+eps)h+agg + Lin/BN/ReLU/Lin/BN/ReLU + pool -------
template<int K, bool LAST>
__global__ __launch_bounds__(256) void gin_layer_kernel(
    const ushort* __restrict__ h_in,   // bf16 [N,K]
    const int* __restrict__ rowptr, const int* __restrict__ col,
    const float* __restrict__ eps_arr, int l,
    const float* __restrict__ W1, const float* __restrict__ b1,   // fp32 [K,64],[64]
    const float* __restrict__ W2, const float* __restrict__ b2,   // fp32 [64,64],[64]
    const float* __restrict__ g_a, const float* __restrict__ be_a,
    const float* __restrict__ m_a, const float* __restrict__ v_a,
    const float* __restrict__ g_b, const float* __restrict__ be_b,
    const float* __restrict__ m_b, const float* __restrict__ v_b,
    const int* __restrict__ batch,
    ushort* __restrict__ h_out,        // bf16 [N,64]
    float* __restrict__ readout,       // fp32 [G,320]
    int layer_off)
{
    __shared__ uint W1p[(K / 2) * 64];           // bf16-pair packed: (k2, c)
    __shared__ uint W2p[32 * 64];
    __shared__ float zs[4][K];
    __shared__ __align__(16) int idxs[4][64];

    for (int i = threadIdx.x; i < (K / 2) * 64; i += 256) {
        int k2 = i >> 6, c = i & 63;
        W1p[i] = pack2(W1[(2 * k2) * 64 + c], W1[(2 * k2 + 1) * 64 + c]);
    }
    for (int i = threadIdx.x; i < 32 * 64; i += 256) {
        int k2 = i >> 6, c = i & 63;
        W2p[i] = pack2(W2[(2 * k2) * 64 + c], W2[(2 * k2 + 1) * 64 + c]);
    }

    const int lane = threadIdx.x & 63;
    const int wave = threadIdx.x >> 6;
    const float eps_l = 1.0f + eps_arr[l];
    const float sa  = g_a[lane] * rsqrtf(v_a[lane] + 1e-5f);
    const float sha = be_a[lane] - m_a[lane] * sa;
    const float sb  = g_b[lane] * rsqrtf(v_b[lane] + 1e-5f);
    const float shb = be_b[lane] - m_b[lane] * sb;
    const float bias1 = b1[lane];
    const float bias2 = b2[lane];
    __syncthreads();

    const int ngroups = (NN + 3) >> 2;
    for (int grp = blockIdx.x; grp < ngroups; grp += gridDim.x) {
        const int row = grp * 4 + wave;
        if (row < NN) {
            const int rs = rowptr[row];
            const int re = rowptr[row + 1];

            // ---- gather: agg = sum h_in[neigh]; LDS-staged indices, 4-8 loads in flight ----
            if constexpr (K == 64) {
                float acc = 0.f;
                for (int j = rs; j < re; j += 64) {
                    const int cnt = (re - j < 64) ? (re - j) : 64;
                    if (lane < cnt) idxs[wave][lane] = col[j + lane];
                    int t = 0;
                    for (; t + 8 <= cnt; t += 8) {
                        int4 sa4 = *(const int4*)&idxs[wave][t];
                        int4 sb4 = *(const int4*)&idxs[wave][t + 4];
                        float v0 = bf2f(h_in[(size_t)sa4.x * 64 + lane]);
                        float v1 = bf2f(h_in[(size_t)sa4.y * 64 + lane]);
                        float v2 = bf2f(h_in[(size_t)sa4.z * 64 + lane]);
                        float v3 = bf2f(h_in[(size_t)sa4.w * 64 + lane]);
                        float v4 = bf2f(h_in[(size_t)sb4.x * 64 + lane]);
                        float v5 = bf2f(h_in[(size_t)sb4.y * 64 + lane]);
                        float v6 = bf2f(h_in[(size_t)sb4.z * 64 + lane]);
                        float v7 = bf2f(h_in[(size_t)sb4.w * 64 + lane]);
                        acc += ((v0 + v1) + (v2 + v3)) + ((v4 + v5) + (v6 + v7));
                    }
                    for (; t + 4 <= cnt; t += 4) {
                        int4 s4 = *(const int4*)&idxs[wave][t];
                        float v0 = bf2f(h_in[(size_t)s4.x * 64 + lane]);
                        float v1 = bf2f(h_in[(size_t)s4.y * 64 + lane]);
                        float v2 = bf2f(h_in[(size_t)s4.z * 64 + lane]);
                        float v3 = bf2f(h_in[(size_t)s4.w * 64 + lane]);
                        acc += (v0 + v1) + (v2 + v3);
                    }
                    for (; t < cnt; ++t) {
                        int s = idxs[wave][t];
                        acc += bf2f(h_in[(size_t)s * 64 + lane]);
                    }
                }
                zs[wave][lane] = eps_l * bf2f(h_in[(size_t)row * 64 + lane]) + acc;
            } else {
                const uint* h32 = (const uint*)h_in;   // pair-packed rows of 64 uints
                float acc0 = 0.f, acc1 = 0.f;
                for (int j = rs; j < re; j += 64) {
                    const int cnt = (re - j < 64) ? (re - j) : 64;
                    if (lane < cnt) idxs[wave][lane] = col[j + lane];
                    int t = 0;
                    for (; t + 4 <= cnt; t += 4) {
                        int4 s4 = *(const int4*)&idxs[wave][t];
                        uint p0 = h32[(size_t)s4.x * 64 + lane];
                        uint p1 = h32[(size_t)s4.y * 64 + lane];
                        uint p2 = h32[(size_t)s4.z * 64 + lane];
                        uint p3 = h32[(size_t)s4.w * 64 + lane];
                        acc0 += (lo16(p0) + lo16(p1)) + (lo16(p2) + lo16(p3));
                        acc1 += (hi16(p0) + hi16(p1)) + (hi16(p2) + hi16(p3));
                    }
                    for (; t < cnt; ++t) {
                        uint p = h32[(size_t)idxs[wave][t] * 64 + lane];
                        acc0 += lo16(p);
                        acc1 += hi16(p);
                    }
                }
                uint pr = h32[(size_t)row * 64 + lane];
                zs[wave][2 * lane]     = eps_l * lo16(pr) + acc0;
                zs[wave][2 * lane + 1] = eps_l * hi16(pr) + acc1;
            }
            // wave-private LDS row; per-wave LDS ops are in-order -> no barrier

            // ---- z @ W1 (+b1) -> BN -> ReLU ----
            float a0 = 0.f, a1 = 0.f;
            #pragma unroll
            for (int k2 = 0; k2 < K / 2; ++k2) {
                uint wp = W1p[k2 * 64 + lane];
                float2 z2 = *(const float2*)&zs[wave][2 * k2];
                a0 = fmaf(z2.x, lo16(wp), a0);
                a1 = fmaf(z2.y, hi16(wp), a1);
            }
            float z1 = bias1 + (a0 + a1);
            float v1 = fmaxf(z1 * sa + sha, 0.0f);

            zs[wave][lane] = v1;

            // ---- v1 @ W2 (+b2) -> BN -> ReLU ----
            float c0 = 0.f, c1 = 0.f;
            #pragma unroll
            for (int k2 = 0; k2 < 32; ++k2) {
                uint wp = W2p[k2 * 64 + lane];
                float2 z2 = *(const float2*)&zs[wave][2 * k2];
                c0 = fmaf(z2.x, lo16(wp), c0);
                c1 = fmaf(z2.y, hi16(wp), c1);
            }
            float z2v = bias2 + (c0 + c1);
            float v2 = fmaxf(z2v * sb + shb, 0.0f);

            if (!LAST) h_out[(size_t)row * 64 + lane] = f2bf(v2);
            const int g = batch[row];
            unsafeAtomicAdd(readout + (size_t)g * RCOLS + layer_off + lane, v2);
        }
    }
}

// ---------------- final graph-level GEMM: [G,320] @ [320,16] + bc ----------------
__global__ __launch_bounds__(256) void final_gemm(
    const float* __restrict__ R, const float* __restrict__ Wc,
    const float* __restrict__ bc, float* __restrict__ out)
{
    const int tid = blockIdx.x * 256 + threadIdx.x;
    if (tid >= GG * OUTC) return;
    const int g = tid >> 4;
    const int o = tid & 15;
    float acc = bc[o];
    const float* r = R + (size_t)g * RCOLS;
    #pragma unroll 8
    for (int k = 0; k < RCOLS; ++k)
        acc += r[k] * Wc[k * OUTC + o];
    out[tid] = acc;
}

extern "C" void kernel_launch(void* const* d_in, const int* in_sizes, int n_in,
                              void* d_out, int out_size, void* d_ws, size_t ws_size,
                              hipStream_t stream)
{
    const float* x    = (const float*)d_in[0];
    const int*   ei   = (const int*)d_in[1];
    const int*   batch= (const int*)d_in[2];
    const float* eps  = (const float*)d_in[3];
    const float* W1_0 = (const float*)d_in[4];
    const float* b1_0 = (const float*)d_in[5];
    const float* W1_r = (const float*)d_in[6];
    const float* b1_r = (const float*)d_in[7];
    const float* g_a  = (const float*)d_in[8];
    const float* be_a = (const float*)d_in[9];
    const float* m_a  = (const float*)d_in[10];
    const float* v_a  = (const float*)d_in[11];
    const float* W2   = (const float*)d_in[12];
    const float* b2   = (const float*)d_in[13];
    const float* g_b  = (const float*)d_in[14];
    const float* be_b = (const float*)d_in[15];
    const float* m_b  = (const float*)d_in[16];
    const float* v_b  = (const float*)d_in[17];
    const float* Wc   = (const float*)d_in[18];
    const float* bc   = (const float*)d_in[19];
    float* out = (float*)d_out;

    const int* src = ei;
    const int* dst = ei + EE;

    // workspace layout (bytes)
    char* ws = (char*)d_ws;
    int*    rowptr  = (int*)(ws);                        // 400KB
    int*    deg     = (int*)(ws + 524288);
    int*    cursor  = (int*)(ws + 1048576);
    int*    col     = (int*)(ws + 1572864);              // 6.4MB
    uint*   xb      = (uint*)(ws + 8388608);             // N*64*4 = 25.6MB (bf16 pairs)
    ushort* h_a     = (ushort*)(ws + 33988608);          // N*64*2 = 12.8MB
    ushort* h_b     = (ushort*)(ws + 46788608);          // 12.8MB
    float*  readout = (float*)(ws + 59588608);           // 640KB

    hipMemsetAsync(deg, 0, (size_t)NN * 4, stream);
    hipMemsetAsync(readout, 0, (size_t)GG * RCOLS * 4, stream);

    hist_kernel<<<2048, 256, 0, stream>>>(dst, deg);
    cvt_x_kernel<<<2048, 256, 0, stream>>>(x, xb);
    scan_kernel<<<1, 1024, 0, stream>>>(deg, rowptr, cursor);
    fill_kernel<<<2048, 256, 0, stream>>>(src, dst, cursor, col);

    ushort* h_cur = h_a;
    ushort* h_nxt = h_b;

    for (int l = 0; l < LL; ++l) {
        const ushort* hin = (l == 0) ? (const ushort*)xb : h_cur;
        const float* W1 = (l == 0) ? W1_0 : (W1_r + (size_t)(l - 1) * 64 * 64);
        const float* b1 = (l == 0) ? b1_0 : (b1_r + (size_t)(l - 1) * 64);
        const int off = l * 64;
        if (l == 0) {
            gin_layer_kernel<128, false><<<2048, 256, 0, stream>>>(
                hin, rowptr, col, eps, l, W1, b1,
                W2 + (size_t)l * 64 * 64, b2 + off,
                g_a + off, be_a + off, m_a + off, v_a + off,
                g_b + off, be_b + off, m_b + off, v_b + off,
                batch, h_nxt, readout, off);
        } else if (l < LL - 1) {
            gin_layer_kernel<64, false><<<2048, 256, 0, stream>>>(
                hin, rowptr, col, eps, l, W1, b1,
                W2 + (size_t)l * 64 * 64, b2 + off,
                g_a + off, be_a + off, m_a + off, v_a + off,
                g_b + off, be_b + off, m_b + off, v_b + off,
                batch, h_nxt, readout, off);
        } else {
            gin_layer_kernel<64, true><<<2048, 256, 0, stream>>>(
                hin, rowptr, col, eps, l, W1, b1,
                W2 + (size_t)l * 64 * 64, b2 + off,
                g_a + off, be_a + off, m_a + off, v_a + off,
                g_b + off, be_b + off, m_b + off, v_b + off,
                batch, h_nxt, readout, off);
        }
        ushort* t = h_cur; h_cur = h_nxt; h_nxt = t;
    }

    final_gemm<<<(GG * OUTC + 255) / 256, 256, 0, stream>>>(readout, Wc, bc, out);
}

// Round 4
// 816.478 us; speedup vs baseline: 10.6316x; 1.2523x over previous
//
#include <hip/hip_runtime.h>

#define NN 100000
#define EE 1600000
#define GG 512
#define LL 5
#define HID 64
#define RCOLS (HID*LL)   // 320
#define OUTC 16
#define NBLK ((NN + 255) / 256)   // 391

typedef unsigned int uint;
typedef unsigned short ushort;

__device__ __forceinline__ float bf2f(ushort u) {
    return __uint_as_float(((uint)u) << 16);
}
__device__ __forceinline__ ushort f2bf(float f) {
    uint u = __float_as_uint(f);
    u = (u + 0x7fffu + ((u >> 16) & 1u)) >> 16;   // round-to-nearest-even
    return (ushort)u;
}
__device__ __forceinline__ uint pack2(float a, float b) {
    return (uint)f2bf(a) | ((uint)f2bf(b) << 16);
}
__device__ __forceinline__ float lo16(uint p) { return __uint_as_float(p << 16); }
__device__ __forceinline__ float hi16(uint p) { return __uint_as_float(p & 0xffff0000u); }

// ---------------- CSR build: histogram -> 3-stage parallel scan -> fill ----------------
__global__ __launch_bounds__(256) void hist_kernel(
    const int* __restrict__ dst, int* __restrict__ deg)
{
    for (int e = blockIdx.x * 256 + threadIdx.x; e < EE; e += gridDim.x * 256)
        atomicAdd(&deg[dst[e]], 1);
}

// stage 1: per-block sum of 256 degrees
__global__ __launch_bounds__(256) void scan1_kernel(
    const int* __restrict__ deg, int* __restrict__ bsums)
{
    const int i = blockIdx.x * 256 + threadIdx.x;
    int v = (i < NN) ? deg[i] : 0;
    // wave reduce
    for (int off = 32; off > 0; off >>= 1) v += __shfl_down(v, off, 64);
    __shared__ int part[4];
    if ((threadIdx.x & 63) == 0) part[threadIdx.x >> 6] = v;
    __syncthreads();
    if (threadIdx.x == 0)
        bsums[blockIdx.x] = part[0] + part[1] + part[2] + part[3];
}

// stage 2: single-block exclusive scan of NBLK block sums
__global__ __launch_bounds__(512) void scan2_kernel(
    int* __restrict__ bsums, int* __restrict__ boffs, int* __restrict__ rowptr)
{
    __shared__ int s[512];
    const int t = threadIdx.x;
    int v = (t < NBLK) ? bsums[t] : 0;
    s[t] = v;
    __syncthreads();
    int val = v;
    for (int off = 1; off < 512; off <<= 1) {
        int other = (t >= off) ? s[t - off] : 0;
        __syncthreads();
        val += other;
        s[t] = val;
        __syncthreads();
    }
    if (t < NBLK) boffs[t] = val - v;   // exclusive
    if (t == 0) rowptr[NN] = EE;
}

// stage 3: in-block scan + block offset -> rowptr/cursor
__global__ __launch_bounds__(256) void scan3_kernel(
    const int* __restrict__ deg, const int* __restrict__ boffs,
    int* __restrict__ rowptr, int* __restrict__ cursor)
{
    __shared__ int s[256];
    const int t = threadIdx.x;
    const int i = blockIdx.x * 256 + t;
    int v = (i < NN) ? deg[i] : 0;
    s[t] = v;
    __syncthreads();
    int val = v;
    for (int off = 1; off < 256; off <<= 1) {
        int other = (t >= off) ? s[t - off] : 0;
        __syncthreads();
        val += other;
        s[t] = val;
        __syncthreads();
    }
    if (i < NN) {
        int r = boffs[blockIdx.x] + val - v;   // exclusive prefix
        rowptr[i] = r;
        cursor[i] = r;
    }
}

__global__ __launch_bounds__(256) void fill_kernel(
    const int* __restrict__ src, const int* __restrict__ dst,
    int* __restrict__ cursor, int* __restrict__ col)
{
    for (int e = blockIdx.x * 256 + threadIdx.x; e < EE; e += gridDim.x * 256) {
        int d = dst[e];
        int p = atomicAdd(&cursor[d], 1);
        col[p] = src[e];
    }
}

// ---------------- x (fp32 [N,128]) -> bf16-pair-packed [N,64] uints ----------------
__global__ __launch_bounds__(256) void cvt_x_kernel(
    const float* __restrict__ x, uint* __restrict__ xb)
{
    for (int i = blockIdx.x * 256 + threadIdx.x; i < NN * 64; i += gridDim.x * 256) {
        float2 v = ((const float2*)x)[i];
        xb[i] = pack2(v.x, v.y);
    }
}

// ------- fused layer: CSR gather(bf16) + (1+eps)h+agg + Lin/BN/ReLU/Lin/BN/ReLU + pool -------
template<int K, bool LAST>
__global__ __launch_bounds__(256) void gin_layer_kernel(
    const ushort* __restrict__ h_in,   // bf16 [N,K]
    const int* __restrict__ rowptr, const int* __restrict__ col,
    const float* __restrict__ eps_arr, int l,
    const float* __restrict__ W1, const float* __restrict__ b1,   // fp32 [K,64],[64]
    const float* __restrict__ W2, const float* __restrict__ b2,   // fp32 [64,64],[64]
    const float* __restrict__ g_a, const float* __restrict__ be_a,
    const float* __restrict__ m_a, const float* __restrict__ v_a,
    const float* __restrict__ g_b, const float* __restrict__ be_b,
    const float* __restrict__ m_b, const float* __restrict__ v_b,
    const int* __restrict__ batch,
    ushort* __restrict__ h_out,        // bf16 [N,64]
    float* __restrict__ readout,       // fp32 [G,320]
    int layer_off)
{
    __shared__ uint W1p[(K / 2) * 64];           // bf16-pair packed: (k2, c)
    __shared__ uint W2p[32 * 64];
    __shared__ float zs[4][K];
    __shared__ __align__(16) int idxs[4][64];

    for (int i = threadIdx.x; i < (K / 2) * 64; i += 256) {
        int k2 = i >> 6, c = i & 63;
        W1p[i] = pack2(W1[(2 * k2) * 64 + c], W1[(2 * k2 + 1) * 64 + c]);
    }
    for (int i = threadIdx.x; i < 32 * 64; i += 256) {
        int k2 = i >> 6, c = i & 63;
        W2p[i] = pack2(W2[(2 * k2) * 64 + c], W2[(2 * k2 + 1) * 64 + c]);
    }

    const int lane = threadIdx.x & 63;
    const int wave = threadIdx.x >> 6;
    const float eps_l = 1.0f + eps_arr[l];
    const float sa  = g_a[lane] * rsqrtf(v_a[lane] + 1e-5f);
    const float sha = be_a[lane] - m_a[lane] * sa;
    const float sb  = g_b[lane] * rsqrtf(v_b[lane] + 1e-5f);
    const float shb = be_b[lane] - m_b[lane] * sb;
    const float bias1 = b1[lane];
    const float bias2 = b2[lane];
    __syncthreads();

    const int ngroups = (NN + 3) >> 2;
    for (int grp = blockIdx.x; grp < ngroups; grp += gridDim.x) {
        const int row = grp * 4 + wave;
        if (row < NN) {
            const int rs = rowptr[row];
            const int re = rowptr[row + 1];

            // ---- gather: agg = sum h_in[neigh]; LDS-staged indices, 4-8 loads in flight ----
            if constexpr (K == 64) {
                float acc = 0.f;
                for (int j = rs; j < re; j += 64) {
                    const int cnt = (re - j < 64) ? (re - j) : 64;
                    if (lane < cnt) idxs[wave][lane] = col[j + lane];
                    int t = 0;
                    for (; t + 8 <= cnt; t += 8) {
                        int4 sa4 = *(const int4*)&idxs[wave][t];
                        int4 sb4 = *(const int4*)&idxs[wave][t + 4];
                        float v0 = bf2f(h_in[(size_t)sa4.x * 64 + lane]);
                        float v1 = bf2f(h_in[(size_t)sa4.y * 64 + lane]);
                        float v2 = bf2f(h_in[(size_t)sa4.z * 64 + lane]);
                        float v3 = bf2f(h_in[(size_t)sa4.w * 64 + lane]);
                        float v4 = bf2f(h_in[(size_t)sb4.x * 64 + lane]);
                        float v5 = bf2f(h_in[(size_t)sb4.y * 64 + lane]);
                        float v6 = bf2f(h_in[(size_t)sb4.z * 64 + lane]);
                        float v7 = bf2f(h_in[(size_t)sb4.w * 64 + lane]);
                        acc += ((v0 + v1) + (v2 + v3)) + ((v4 + v5) + (v6 + v7));
                    }
                    for (; t + 4 <= cnt; t += 4) {
                        int4 s4 = *(const int4*)&idxs[wave][t];
                        float v0 = bf2f(h_in[(size_t)s4.x * 64 + lane]);
                        float v1 = bf2f(h_in[(size_t)s4.y * 64 + lane]);
                        float v2 = bf2f(h_in[(size_t)s4.z * 64 + lane]);
                        float v3 = bf2f(h_in[(size_t)s4.w * 64 + lane]);
                        acc += (v0 + v1) + (v2 + v3);
                    }
                    for (; t < cnt; ++t) {
                        int s = idxs[wave][t];
                        acc += bf2f(h_in[(size_t)s * 64 + lane]);
                    }
                }
                zs[wave][lane] = eps_l * bf2f(h_in[(size_t)row * 64 + lane]) + acc;
            } else {
                const uint* h32 = (const uint*)h_in;   // pair-packed rows of 64 uints
                float acc0 = 0.f, acc1 = 0.f;
                for (int j = rs; j < re; j += 64) {
                    const int cnt = (re - j < 64) ? (re - j) : 64;
                    if (lane < cnt) idxs[wave][lane] = col[j + lane];
                    int t = 0;
                    for (; t + 4 <= cnt; t += 4) {
                        int4 s4 = *(const int4*)&idxs[wave][t];
                        uint p0 = h32[(size_t)s4.x * 64 + lane];
                        uint p1 = h32[(size_t)s4.y * 64 + lane];
                        uint p2 = h32[(size_t)s4.z * 64 + lane];
                        uint p3 = h32[(size_t)s4.w * 64 + lane];
                        acc0 += (lo16(p0) + lo16(p1)) + (lo16(p2) + lo16(p3));
                        acc1 += (hi16(p0) + hi16(p1)) + (hi16(p2) + hi16(p3));
                    }
                    for (; t < cnt; ++t) {
                        uint p = h32[(size_t)idxs[wave][t] * 64 + lane];
                        acc0 += lo16(p);
                        acc1 += hi16(p);
                    }
                }
                uint pr = h32[(size_t)row * 64 + lane];
                zs[wave][2 * lane]     = eps_l * lo16(pr) + acc0;
                zs[wave][2 * lane + 1] = eps_l * hi16(pr) + acc1;
            }
            // wave-private LDS row; per-wave LDS ops are in-order -> no barrier

            // ---- z @ W1 (+b1) -> BN -> ReLU ----
            float a0 = 0.f, a1 = 0.f;
            #pragma unroll
            for (int k2 = 0; k2 < K / 2; ++k2) {
                uint wp = W1p[k2 * 64 + lane];
                float2 z2 = *(const float2*)&zs[wave][2 * k2];
                a0 = fmaf(z2.x, lo16(wp), a0);
                a1 = fmaf(z2.y, hi16(wp), a1);
            }
            float z1 = bias1 + (a0 + a1);
            float v1 = fmaxf(z1 * sa + sha, 0.0f);

            zs[wave][lane] = v1;

            // ---- v1 @ W2 (+b2) -> BN -> ReLU ----
            float c0 = 0.f, c1 = 0.f;
            #pragma unroll
            for (int k2 = 0; k2 < 32; ++k2) {
                uint wp = W2p[k2 * 64 + lane];
                float2 z2 = *(const float2*)&zs[wave][2 * k2];
                c0 = fmaf(z2.x, lo16(wp), c0);
                c1 = fmaf(z2.y, hi16(wp), c1);
            }
            float z2v = bias2 + (c0 + c1);
            float v2 = fmaxf(z2v * sb + shb, 0.0f);

            if (!LAST) h_out[(size_t)row * 64 + lane] = f2bf(v2);
            const int g = batch[row];
            unsafeAtomicAdd(readout + (size_t)g * RCOLS + layer_off + lane, v2);
        }
    }
}

// ---------------- final graph-level GEMM: [G,320] @ [320,16] + bc ----------------
__global__ __launch_bounds__(256) void final_gemm(
    const float* __restrict__ R, const float* __restrict__ Wc,
    const float* __restrict__ bc, float* __restrict__ out)
{
    const int tid = blockIdx.x * 256 + threadIdx.x;
    if (tid >= GG * OUTC) return;
    const int g = tid >> 4;
    const int o = tid & 15;
    float acc = bc[o];
    const float* r = R + (size_t)g * RCOLS;
    #pragma unroll 8
    for (int k = 0; k < RCOLS; ++k)
        acc += r[k] * Wc[k * OUTC + o];
    out[tid] = acc;
}

extern "C" void kernel_launch(void* const* d_in, const int* in_sizes, int n_in,
                              void* d_out, int out_size, void* d_ws, size_t ws_size,
                              hipStream_t stream)
{
    const float* x    = (const float*)d_in[0];
    const int*   ei   = (const int*)d_in[1];
    const int*   batch= (const int*)d_in[2];
    const float* eps  = (const float*)d_in[3];
    const float* W1_0 = (const float*)d_in[4];
    const float* b1_0 = (const float*)d_in[5];
    const float* W1_r = (const float*)d_in[6];
    const float* b1_r = (const float*)d_in[7];
    const float* g_a  = (const float*)d_in[8];
    const float* be_a = (const float*)d_in[9];
    const float* m_a  = (const float*)d_in[10];
    const float* v_a  = (const float*)d_in[11];
    const float* W2   = (const float*)d_in[12];
    const float* b2   = (const float*)d_in[13];
    const float* g_b  = (const float*)d_in[14];
    const float* be_b = (const float*)d_in[15];
    const float* m_b  = (const float*)d_in[16];
    const float* v_b  = (const float*)d_in[17];
    const float* Wc   = (const float*)d_in[18];
    const float* bc   = (const float*)d_in[19];
    float* out = (float*)d_out;

    const int* src = ei;
    const int* dst = ei + EE;

    // workspace layout (bytes)
    char* ws = (char*)d_ws;
    int*    rowptr  = (int*)(ws);                        // 400KB+
    int*    deg     = (int*)(ws + 524288);
    int*    cursor  = (int*)(ws + 1048576);
    int*    bsums   = (int*)(ws + 1441792);              // NBLK ints
    int*    boffs   = (int*)(ws + 1507328);              // NBLK ints
    int*    col     = (int*)(ws + 1572864);              // 6.4MB
    uint*   xb      = (uint*)(ws + 8388608);             // N*64*4 = 25.6MB (bf16 pairs)
    ushort* h_a     = (ushort*)(ws + 33988608);          // N*64*2 = 12.8MB
    ushort* h_b     = (ushort*)(ws + 46788608);          // 12.8MB
    float*  readout = (float*)(ws + 59588608);           // 640KB

    hipMemsetAsync(deg, 0, (size_t)NN * 4, stream);
    hipMemsetAsync(readout, 0, (size_t)GG * RCOLS * 4, stream);

    hist_kernel<<<2048, 256, 0, stream>>>(dst, deg);
    cvt_x_kernel<<<2048, 256, 0, stream>>>(x, xb);
    scan1_kernel<<<NBLK, 256, 0, stream>>>(deg, bsums);
    scan2_kernel<<<1, 512, 0, stream>>>(bsums, boffs, rowptr);
    scan3_kernel<<<NBLK, 256, 0, stream>>>(deg, boffs, rowptr, cursor);
    fill_kernel<<<2048, 256, 0, stream>>>(src, dst, cursor, col);

    ushort* h_cur = h_a;
    ushort* h_nxt = h_b;

    for (int l = 0; l < LL; ++l) {
        const ushort* hin = (l == 0) ? (const ushort*)xb : h_cur;
        const float* W1 = (l == 0) ? W1_0 : (W1_r + (size_t)(l - 1) * 64 * 64);
        const float* b1 = (l == 0) ? b1_0 : (b1_r + (size_t)(l - 1) * 64);
        const int off = l * 64;
        if (l == 0) {
            gin_layer_kernel<128, false><<<2048, 256, 0, stream>>>(
                hin, rowptr, col, eps, l, W1, b1,
                W2 + (size_t)l * 64 * 64, b2 + off,
                g_a + off, be_a + off, m_a + off, v_a + off,
                g_b + off, be_b + off, m_b + off, v_b + off,
                batch, h_nxt, readout, off);
        } else if (l < LL - 1) {
            gin_layer_kernel<64, false><<<2048, 256, 0, stream>>>(
                hin, rowptr, col, eps, l, W1, b1,
                W2 + (size_t)l * 64 * 64, b2 + off,
                g_a + off, be_a + off, m_a + off, v_a + off,
                g_b + off, be_b + off, m_b + off, v_b + off,
                batch, h_nxt, readout, off);
        } else {
            gin_layer_kernel<64, true><<<2048, 256, 0, stream>>>(
                hin, rowptr, col, eps, l, W1, b1,
                W2 + (size_t)l * 64 * 64, b2 + off,
                g_a + off, be_a + off, m_a + off, v_a + off,
                g_b + off, be_b + off, m_b + off, v_b + off,
                batch, h_nxt, readout, off);
        }
        ushort* t = h_cur; h_cur = h_nxt; h_nxt = t;
    }

    final_gemm<<<(GG * OUTC + 255) / 256, 256, 0, stream>>>(readout, Wc, bc, out);
}

// Round 5
// 736.918 us; speedup vs baseline: 11.7794x; 1.1080x over previous
//
#include <hip/hip_runtime.h>

#define NN 100000
#define EE 1600000
#define GG 512
#define LL 5
#define HID 64
#define RCOLS (HID*LL)   // 320
#define OUTC 16
#define NBLK ((NN + 255) / 256)   // 391

typedef unsigned int uint;
typedef unsigned short ushort;
typedef __attribute__((ext_vector_type(8))) short short8;
typedef __attribute__((ext_vector_type(4))) float f32x4;

__device__ __forceinline__ float bf2f(ushort u) {
    return __uint_as_float(((uint)u) << 16);
}
__device__ __forceinline__ ushort f2bf(float f) {
    uint u = __float_as_uint(f);
    u = (u + 0x7fffu + ((u >> 16) & 1u)) >> 16;   // round-to-nearest-even
    return (ushort)u;
}
__device__ __forceinline__ uint pack2(float a, float b) {
    return (uint)f2bf(a) | ((uint)f2bf(b) << 16);
}
__device__ __forceinline__ float lo16(uint p) { return __uint_as_float(p << 16); }
__device__ __forceinline__ float hi16(uint p) { return __uint_as_float(p & 0xffff0000u); }

// ---------------- CSR build: histogram -> 3-stage parallel scan -> fill ----------------
__global__ __launch_bounds__(256) void hist_kernel(
    const int* __restrict__ dst, int* __restrict__ deg)
{
    for (int e = blockIdx.x * 256 + threadIdx.x; e < EE; e += gridDim.x * 256)
        atomicAdd(&deg[dst[e]], 1);
}

__global__ __launch_bounds__(256) void scan1_kernel(
    const int* __restrict__ deg, int* __restrict__ bsums)
{
    const int i = blockIdx.x * 256 + threadIdx.x;
    int v = (i < NN) ? deg[i] : 0;
    for (int off = 32; off > 0; off >>= 1) v += __shfl_down(v, off, 64);
    __shared__ int part[4];
    if ((threadIdx.x & 63) == 0) part[threadIdx.x >> 6] = v;
    __syncthreads();
    if (threadIdx.x == 0)
        bsums[blockIdx.x] = part[0] + part[1] + part[2] + part[3];
}

__global__ __launch_bounds__(512) void scan2_kernel(
    int* __restrict__ bsums, int* __restrict__ boffs, int* __restrict__ rowptr)
{
    __shared__ int s[512];
    const int t = threadIdx.x;
    int v = (t < NBLK) ? bsums[t] : 0;
    s[t] = v;
    __syncthreads();
    int val = v;
    for (int off = 1; off < 512; off <<= 1) {
        int other = (t >= off) ? s[t - off] : 0;
        __syncthreads();
        val += other;
        s[t] = val;
        __syncthreads();
    }
    if (t < NBLK) boffs[t] = val - v;
    if (t == 0) rowptr[NN] = EE;
}

__global__ __launch_bounds__(256) void scan3_kernel(
    const int* __restrict__ deg, const int* __restrict__ boffs,
    int* __restrict__ rowptr, int* __restrict__ cursor)
{
    __shared__ int s[256];
    const int t = threadIdx.x;
    const int i = blockIdx.x * 256 + t;
    int v = (i < NN) ? deg[i] : 0;
    s[t] = v;
    __syncthreads();
    int val = v;
    for (int off = 1; off < 256; off <<= 1) {
        int other = (t >= off) ? s[t - off] : 0;
        __syncthreads();
        val += other;
        s[t] = val;
        __syncthreads();
    }
    if (i < NN) {
        int r = boffs[blockIdx.x] + val - v;
        rowptr[i] = r;
        cursor[i] = r;
    }
}

__global__ __launch_bounds__(256) void fill_kernel(
    const int* __restrict__ src, const int* __restrict__ dst,
    int* __restrict__ cursor, int* __restrict__ col)
{
    for (int e = blockIdx.x * 256 + threadIdx.x; e < EE; e += gridDim.x * 256) {
        int d = dst[e];
        int p = atomicAdd(&cursor[d], 1);
        col[p] = src[e];
    }
}

// ---------------- x (fp32 [N,128]) -> bf16-pair-packed [N,64] uints ----------------
__global__ __launch_bounds__(256) void cvt_x_kernel(
    const float* __restrict__ x, uint* __restrict__ xb)
{
    for (int i = blockIdx.x * 256 + threadIdx.x; i < NN * 64; i += gridDim.x * 256) {
        float2 v = ((const float2*)x)[i];
        xb[i] = pack2(v.x, v.y);
    }
}

// ------- fused layer: CSR gather(bf16) -> wave-private LDS z-tile -> MFMA MLP -> pool -------
// Each wave owns 16 consecutive rows; no inter-wave barriers in the main loop.
// mfma(X-frag, Y-frag) computes X·Y^T with both frags k-contiguous per lane,
// C/D: col=lane&15, row=(lane>>4)*4+reg (m89-verified layout).
template<int K, bool LAST>
__global__ __launch_bounds__(256, 4) void gin_layer_kernel(
    const ushort* __restrict__ h_in,   // bf16 [N,K]
    const int* __restrict__ rowptr, const int* __restrict__ col,
    const float* __restrict__ eps_arr, int l,
    const float* __restrict__ W1, const float* __restrict__ b1,   // fp32 [K,64],[64]
    const float* __restrict__ W2, const float* __restrict__ b2,   // fp32 [64,64],[64]
    const float* __restrict__ g_a, const float* __restrict__ be_a,
    const float* __restrict__ m_a, const float* __restrict__ v_a,
    const float* __restrict__ g_b, const float* __restrict__ be_b,
    const float* __restrict__ m_b, const float* __restrict__ v_b,
    const int* __restrict__ batch,
    ushort* __restrict__ h_out,        // bf16 [N,64]
    float* __restrict__ readout,       // fp32 [G,320]
    int layer_off)
{
    constexpr int PK = K + 8;          // padded row stride (elements); PK*2 % 16 == 0
    __shared__ __align__(16) ushort W1t[64 * PK];     // W1^T [c][k] bf16
    __shared__ __align__(16) ushort W2t[64 * 72];     // W2^T [c][k] bf16
    __shared__ __align__(16) ushort zA[4][16 * PK];   // per-wave z tile [r][k]
    __shared__ float2 bnA[64], bnB[64];
    __shared__ __align__(16) int idxs[4][64];

    for (int e = threadIdx.x; e < 64 * K; e += 256) {
        int c = e & 63, k = e >> 6;
        W1t[c * PK + k] = f2bf(W1[k * 64 + c]);
    }
    for (int e = threadIdx.x; e < 64 * 64; e += 256) {
        int c = e & 63, k = e >> 6;
        W2t[c * 72 + k] = f2bf(W2[k * 64 + c]);
    }
    if (threadIdx.x < 64) {
        int c = threadIdx.x;
        float sa = g_a[c] * rsqrtf(v_a[c] + 1e-5f);
        float sb = g_b[c] * rsqrtf(v_b[c] + 1e-5f);
        bnA[c] = make_float2(sa, be_a[c] + (b1[c] - m_a[c]) * sa);
        bnB[c] = make_float2(sb, be_b[c] + (b2[c] - m_b[c]) * sb);
    }
    const float eps_l = 1.0f + eps_arr[l];
    __syncthreads();

    const int lane = threadIdx.x & 63;
    const int wave = threadIdx.x >> 6;
    const int fr = lane & 15, fq = lane >> 4;
    ushort* zw = zA[wave];
    const int ngroups = (NN + 63) >> 6;

    for (int grp = blockIdx.x; grp < ngroups; grp += gridDim.x) {
        const int base = grp * 64 + wave * 16;
        if (base >= NN) continue;      // NN % 16 == 0: waves are all-valid or all-idle

        // ---- phase 1: gather 16 rows, write z (bf16) into wave-private tile ----
        for (int i = 0; i < 16; ++i) {
            const int row = base + i;
            const int rs = rowptr[row];
            const int re = rowptr[row + 1];
            if constexpr (K == 64) {
                float acc = 0.f;
                for (int j = rs; j < re; j += 64) {
                    const int cnt = (re - j < 64) ? (re - j) : 64;
                    if (lane < cnt) idxs[wave][lane] = col[j + lane];
                    int t = 0;
                    for (; t + 8 <= cnt; t += 8) {
                        int4 sa4 = *(const int4*)&idxs[wave][t];
                        int4 sb4 = *(const int4*)&idxs[wave][t + 4];
                        float v0 = bf2f(h_in[(size_t)sa4.x * 64 + lane]);
                        float v1 = bf2f(h_in[(size_t)sa4.y * 64 + lane]);
                        float v2 = bf2f(h_in[(size_t)sa4.z * 64 + lane]);
                        float v3 = bf2f(h_in[(size_t)sa4.w * 64 + lane]);
                        float v4 = bf2f(h_in[(size_t)sb4.x * 64 + lane]);
                        float v5 = bf2f(h_in[(size_t)sb4.y * 64 + lane]);
                        float v6 = bf2f(h_in[(size_t)sb4.z * 64 + lane]);
                        float v7 = bf2f(h_in[(size_t)sb4.w * 64 + lane]);
                        acc += ((v0 + v1) + (v2 + v3)) + ((v4 + v5) + (v6 + v7));
                    }
                    for (; t + 4 <= cnt; t += 4) {
                        int4 s4 = *(const int4*)&idxs[wave][t];
                        float v0 = bf2f(h_in[(size_t)s4.x * 64 + lane]);
                        float v1 = bf2f(h_in[(size_t)s4.y * 64 + lane]);
                        float v2 = bf2f(h_in[(size_t)s4.z * 64 + lane]);
                        float v3 = bf2f(h_in[(size_t)s4.w * 64 + lane]);
                        acc += (v0 + v1) + (v2 + v3);
                    }
                    for (; t < cnt; ++t) {
                        int s = idxs[wave][t];
                        acc += bf2f(h_in[(size_t)s * 64 + lane]);
                    }
                }
                zw[i * PK + lane] = f2bf(eps_l * bf2f(h_in[(size_t)row * 64 + lane]) + acc);
            } else {
                const uint* h32 = (const uint*)h_in;   // pair-packed rows of 64 uints
                float acc0 = 0.f, acc1 = 0.f;
                for (int j = rs; j < re; j += 64) {
                    const int cnt = (re - j < 64) ? (re - j) : 64;
                    if (lane < cnt) idxs[wave][lane] = col[j + lane];
                    int t = 0;
                    for (; t + 4 <= cnt; t += 4) {
                        int4 s4 = *(const int4*)&idxs[wave][t];
                        uint p0 = h32[(size_t)s4.x * 64 + lane];
                        uint p1 = h32[(size_t)s4.y * 64 + lane];
                        uint p2 = h32[(size_t)s4.z * 64 + lane];
                        uint p3 = h32[(size_t)s4.w * 64 + lane];
                        acc0 += (lo16(p0) + lo16(p1)) + (lo16(p2) + lo16(p3));
                        acc1 += (hi16(p0) + hi16(p1)) + (hi16(p2) + hi16(p3));
                    }
                    for (; t < cnt; ++t) {
                        uint p = h32[(size_t)idxs[wave][t] * 64 + lane];
                        acc0 += lo16(p);
                        acc1 += hi16(p);
                    }
                }
                uint pr = h32[(size_t)row * 64 + lane];
                *(uint*)&zw[i * PK + 2 * lane] =
                    pack2(eps_l * lo16(pr) + acc0, eps_l * hi16(pr) + acc1);
            }
        }

        // ---- phase 2a: C1 = z @ W1 (= mfma(z, W1^T)); BN+ReLU -> zw cols 0..63 ----
        short8 az[K / 32];
        #pragma unroll
        for (int h = 0; h < K / 32; ++h)
            az[h] = *(const short8*)&zw[fr * PK + h * 32 + fq * 8];
        #pragma unroll
        for (int t = 0; t < 4; ++t) {
            f32x4 acc = {0.f, 0.f, 0.f, 0.f};
            #pragma unroll
            for (int h = 0; h < K / 32; ++h) {
                short8 bw = *(const short8*)&W1t[(t * 16 + fr) * PK + h * 32 + fq * 8];
                acc = __builtin_amdgcn_mfma_f32_16x16x32_bf16(az[h], bw, acc, 0, 0, 0);
            }
            float2 bn = bnA[t * 16 + fr];
            #pragma unroll
            for (int r = 0; r < 4; ++r) {
                float v = fmaxf(acc[r] * bn.x + bn.y, 0.f);
                zw[(fq * 4 + r) * PK + t * 16 + fr] = f2bf(v);
            }
        }

        // ---- phase 2b: C2 = v1 @ W2; BN+ReLU -> zw cols 0..63 ----
        short8 a2[2];
        #pragma unroll
        for (int h = 0; h < 2; ++h)
            a2[h] = *(const short8*)&zw[fr * PK + h * 32 + fq * 8];
        #pragma unroll
        for (int t = 0; t < 4; ++t) {
            f32x4 acc = {0.f, 0.f, 0.f, 0.f};
            #pragma unroll
            for (int h = 0; h < 2; ++h) {
                short8 bw = *(const short8*)&W2t[(t * 16 + fr) * 72 + h * 32 + fq * 8];
                acc = __builtin_amdgcn_mfma_f32_16x16x32_bf16(a2[h], bw, acc, 0, 0, 0);
            }
            float2 bn = bnB[t * 16 + fr];
            #pragma unroll
            for (int r = 0; r < 4; ++r) {
                float v = fmaxf(acc[r] * bn.x + bn.y, 0.f);
                zw[(fq * 4 + r) * PK + t * 16 + fr] = f2bf(v);
            }
        }

        // ---- phase 3: h_out stores (coalesced) + run-length-reduced readout atomics ----
        int curg = batch[base];
        float racc = 0.f;
        #pragma unroll 4
        for (int i = 0; i < 16; ++i) {
            const int row = base + i;
            ushort u = zw[i * PK + lane];
            if constexpr (!LAST) h_out[(size_t)row * 64 + lane] = u;
            const int g = batch[row];
            const float v = bf2f(u);
            if (g != curg) {   // wave-uniform branch (batch sorted, value uniform)
                unsafeAtomicAdd(readout + (size_t)curg * RCOLS + layer_off + lane, racc);
                curg = g;
                racc = v;
            } else {
                racc += v;
            }
        }
        unsafeAtomicAdd(readout + (size_t)curg * RCOLS + layer_off + lane, racc);
    }
}

// ---------------- final graph-level GEMM: [G,320] @ [320,16] + bc ----------------
__global__ __launch_bounds__(256) void final_gemm(
    const float* __restrict__ R, const float* __restrict__ Wc,
    const float* __restrict__ bc, float* __restrict__ out)
{
    const int tid = blockIdx.x * 256 + threadIdx.x;
    if (tid >= GG * OUTC) return;
    const int g = tid >> 4;
    const int o = tid & 15;
    float acc = bc[o];
    const float* r = R + (size_t)g * RCOLS;
    #pragma unroll 8
    for (int k = 0; k < RCOLS; ++k)
        acc += r[k] * Wc[k * OUTC + o];
    out[tid] = acc;
}

extern "C" void kernel_launch(void* const* d_in, const int* in_sizes, int n_in,
                              void* d_out, int out_size, void* d_ws, size_t ws_size,
                              hipStream_t stream)
{
    const float* x    = (const float*)d_in[0];
    const int*   ei   = (const int*)d_in[1];
    const int*   batch= (const int*)d_in[2];
    const float* eps  = (const float*)d_in[3];
    const float* W1_0 = (const float*)d_in[4];
    const float* b1_0 = (const float*)d_in[5];
    const float* W1_r = (const float*)d_in[6];
    const float* b1_r = (const float*)d_in[7];
    const float* g_a  = (const float*)d_in[8];
    const float* be_a = (const float*)d_in[9];
    const float* m_a  = (const float*)d_in[10];
    const float* v_a  = (const float*)d_in[11];
    const float* W2   = (const float*)d_in[12];
    const float* b2   = (const float*)d_in[13];
    const float* g_b  = (const float*)d_in[14];
    const float* be_b = (const float*)d_in[15];
    const float* m_b  = (const float*)d_in[16];
    const float* v_b  = (const float*)d_in[17];
    const float* Wc   = (const float*)d_in[18];
    const float* bc   = (const float*)d_in[19];
    float* out = (float*)d_out;

    const int* src = ei;
    const int* dst = ei + EE;

    // workspace layout (bytes)
    char* ws = (char*)d_ws;
    int*    rowptr  = (int*)(ws);                        // 400KB+
    int*    deg     = (int*)(ws + 524288);
    int*    cursor  = (int*)(ws + 1048576);
    int*    bsums   = (int*)(ws + 1441792);
    int*    boffs   = (int*)(ws + 1507328);
    int*    col     = (int*)(ws + 1572864);              // 6.4MB
    uint*   xb      = (uint*)(ws + 8388608);             // N*64*4 = 25.6MB (bf16 pairs)
    ushort* h_a     = (ushort*)(ws + 33988608);          // N*64*2 = 12.8MB
    ushort* h_b     = (ushort*)(ws + 46788608);          // 12.8MB
    float*  readout = (float*)(ws + 59588608);           // 640KB

    hipMemsetAsync(deg, 0, (size_t)NN * 4, stream);
    hipMemsetAsync(readout, 0, (size_t)GG * RCOLS * 4, stream);

    hist_kernel<<<2048, 256, 0, stream>>>(dst, deg);
    cvt_x_kernel<<<2048, 256, 0, stream>>>(x, xb);
    scan1_kernel<<<NBLK, 256, 0, stream>>>(deg, bsums);
    scan2_kernel<<<1, 512, 0, stream>>>(bsums, boffs, rowptr);
    scan3_kernel<<<NBLK, 256, 0, stream>>>(deg, boffs, rowptr, cursor);
    fill_kernel<<<2048, 256, 0, stream>>>(src, dst, cursor, col);

    ushort* h_cur = h_a;
    ushort* h_nxt = h_b;

    for (int l = 0; l < LL; ++l) {
        const ushort* hin = (l == 0) ? (const ushort*)xb : h_cur;
        const float* W1 = (l == 0) ? W1_0 : (W1_r + (size_t)(l - 1) * 64 * 64);
        const float* b1 = (l == 0) ? b1_0 : (b1_r + (size_t)(l - 1) * 64);
        const int off = l * 64;
        if (l == 0) {
            gin_layer_kernel<128, false><<<768, 256, 0, stream>>>(
                hin, rowptr, col, eps, l, W1, b1,
                W2 + (size_t)l * 64 * 64, b2 + off,
                g_a + off, be_a + off, m_a + off, v_a + off,
                g_b + off, be_b + off, m_b + off, v_b + off,
                batch, h_nxt, readout, off);
        } else if (l < LL - 1) {
            gin_layer_kernel<64, false><<<1024, 256, 0, stream>>>(
                hin, rowptr, col, eps, l, W1, b1,
                W2 + (size_t)l * 64 * 64, b2 + off,
                g_a + off, be_a + off, m_a + off, v_a + off,
                g_b + off, be_b + off, m_b + off, v_b + off,
                batch, h_nxt, readout, off);
        } else {
            gin_layer_kernel<64, true><<<1024, 256, 0, stream>>>(
                hin, rowptr, col, eps, l, W1, b1,
                W2 + (size_t)l * 64 * 64, b2 + off,
                g_a + off, be_a + off, m_a + off, v_a + off,
                g_b + off, be_b + off, m_b + off, v_b + off,
                batch, h_nxt, readout, off);
        }
        ushort* t = h_cur; h_cur = h_nxt; h_nxt = t;
    }

    final_gemm<<<(GG * OUTC + 255) / 256, 256, 0, stream>>>(readout, Wc, bc, out);
}

// Round 6
// 599.854 us; speedup vs baseline: 14.4710x; 1.2285x over previous
//
#include <hip/hip_runtime.h>

#define NN 100000
#define EE 1600000
#define GG 512
#define LL 5
#define HID 64
#define RCOLS (HID*LL)   // 320
#define OUTC 16
#define NBLK ((NN + 255) / 256)   // 391
#define NGRP ((NN + 63) / 64)     // 1563

typedef unsigned int uint;
typedef unsigned short ushort;
typedef __attribute__((ext_vector_type(8))) short short8;
typedef __attribute__((ext_vector_type(4))) float f32x4;

__device__ __forceinline__ float bf2f(ushort u) {
    return __uint_as_float(((uint)u) << 16);
}
__device__ __forceinline__ ushort f2bf(float f) {
    uint u = __float_as_uint(f);
    u = (u + 0x7fffu + ((u >> 16) & 1u)) >> 16;   // round-to-nearest-even
    return (ushort)u;
}

// ---------------- CSR build: histogram -> 3-stage parallel scan -> fill ----------------
__global__ __launch_bounds__(256) void hist_kernel(
    const int* __restrict__ dst, int* __restrict__ deg)
{
    for (int e = blockIdx.x * 256 + threadIdx.x; e < EE; e += gridDim.x * 256)
        atomicAdd(&deg[dst[e]], 1);
}

__global__ __launch_bounds__(256) void scan1_kernel(
    const int* __restrict__ deg, int* __restrict__ bsums)
{
    const int i = blockIdx.x * 256 + threadIdx.x;
    int v = (i < NN) ? deg[i] : 0;
    for (int off = 32; off > 0; off >>= 1) v += __shfl_down(v, off, 64);
    __shared__ int part[4];
    if ((threadIdx.x & 63) == 0) part[threadIdx.x >> 6] = v;
    __syncthreads();
    if (threadIdx.x == 0)
        bsums[blockIdx.x] = part[0] + part[1] + part[2] + part[3];
}

__global__ __launch_bounds__(512) void scan2_kernel(
    int* __restrict__ bsums, int* __restrict__ boffs, int* __restrict__ rowptr)
{
    __shared__ int s[512];
    const int t = threadIdx.x;
    int v = (t < NBLK) ? bsums[t] : 0;
    s[t] = v;
    __syncthreads();
    int val = v;
    for (int off = 1; off < 512; off <<= 1) {
        int other = (t >= off) ? s[t - off] : 0;
        __syncthreads();
        val += other;
        s[t] = val;
        __syncthreads();
    }
    if (t < NBLK) boffs[t] = val - v;
    if (t == 0) rowptr[NN] = EE;
}

__global__ __launch_bounds__(256) void scan3_kernel(
    const int* __restrict__ deg, const int* __restrict__ boffs,
    int* __restrict__ rowptr, int* __restrict__ cursor)
{
    __shared__ int s[256];
    const int t = threadIdx.x;
    const int i = blockIdx.x * 256 + t;
    int v = (i < NN) ? deg[i] : 0;
    s[t] = v;
    __syncthreads();
    int val = v;
    for (int off = 1; off < 256; off <<= 1) {
        int other = (t >= off) ? s[t - off] : 0;
        __syncthreads();
        val += other;
        s[t] = val;
        __syncthreads();
    }
    if (i < NN) {
        int r = boffs[blockIdx.x] + val - v;
        rowptr[i] = r;
        cursor[i] = r;
    }
}

__global__ __launch_bounds__(256) void fill_kernel(
    const int* __restrict__ src, const int* __restrict__ dst,
    int* __restrict__ cursor, int* __restrict__ col)
{
    for (int e = blockIdx.x * 256 + threadIdx.x; e < EE; e += gridDim.x * 256) {
        int d = dst[e];
        int p = atomicAdd(&cursor[d], 1);
        col[p] = src[e];
    }
}

// ---------------- y0 = x @ W1_0  (fp32 [N,128] @ [128,64] -> bf16 [N,64]) ----------------
// mfma(A-frag,B-frag) = A·B^T, frags k-contiguous per lane; C/D col=lane&15, row=(lane>>4)*4+r.
__global__ __launch_bounds__(256) void ingemm_kernel(
    const float* __restrict__ x, const float* __restrict__ W1,
    ushort* __restrict__ Y0)
{
    __shared__ __align__(16) ushort W1t[64 * 136];   // W1^T [c][k], k=0..127, pad 136
    __shared__ __align__(16) ushort zA[4][16 * 72];

    for (int e = threadIdx.x; e < 64 * 128; e += 256) {
        int c = e & 63, k = e >> 6;
        W1t[c * 136 + k] = f2bf(W1[k * 64 + c]);
    }
    __syncthreads();

    const int lane = threadIdx.x & 63;
    const int wave = threadIdx.x >> 6;
    const int fr = lane & 15, fq = lane >> 4;
    ushort* zw = zA[wave];

    for (int grp = blockIdx.x; grp < NGRP; grp += gridDim.x) {
        const int base = grp * 64 + wave * 16;
        if (base >= NN) continue;

        short8 az[4];
        #pragma unroll
        for (int h = 0; h < 4; ++h) {
            const float* xp = x + (size_t)(base + fr) * 128 + h * 32 + fq * 8;
            float4 f0 = *(const float4*)xp;
            float4 f1 = *(const float4*)(xp + 4);
            short8 a;
            a[0] = (short)f2bf(f0.x); a[1] = (short)f2bf(f0.y);
            a[2] = (short)f2bf(f0.z); a[3] = (short)f2bf(f0.w);
            a[4] = (short)f2bf(f1.x); a[5] = (short)f2bf(f1.y);
            a[6] = (short)f2bf(f1.z); a[7] = (short)f2bf(f1.w);
            az[h] = a;
        }
        #pragma unroll
        for (int t = 0; t < 4; ++t) {
            f32x4 acc = {0.f, 0.f, 0.f, 0.f};
            #pragma unroll
            for (int h = 0; h < 4; ++h) {
                short8 bw = *(const short8*)&W1t[(t * 16 + fr) * 136 + h * 32 + fq * 8];
                acc = __builtin_amdgcn_mfma_f32_16x16x32_bf16(az[h], bw, acc, 0, 0, 0);
            }
            #pragma unroll
            for (int r = 0; r < 4; ++r)
                zw[(fq * 4 + r) * 72 + t * 16 + fr] = f2bf(acc[r]);
        }
        #pragma unroll 4
        for (int i = 0; i < 16; ++i)
            Y0[(size_t)(base + i) * 64 + lane] = zw[i * 72 + lane];
    }
}

// ------- fused layer on Y = h@W1 (bf16 [N,64]):
//   gather t = (1+eps)*Y[row] + sum Y[neigh]  (this IS z@W1, linear-commute)
//   v1 = relu(t*saA + shA)                     (b1 folded into shA)
//   v2 = relu((v1@W2)*sbB + shB)               (b2 folded into shB)
//   readout[g] += v2 ; if !LAST: Ynext = v2 @ W1next
template<bool LAST>
__global__ __launch_bounds__(256, 5) void gin_layer_kernel(
    const ushort* __restrict__ Y,      // bf16 [N,64]
    const int* __restrict__ rowptr, const int* __restrict__ col,
    const float* __restrict__ eps_arr, int l,
    const float* __restrict__ b1,
    const float* __restrict__ W2, const float* __restrict__ b2,   // fp32 [64,64],[64]
    const float* __restrict__ g_a, const float* __restrict__ be_a,
    const float* __restrict__ m_a, const float* __restrict__ v_a,
    const float* __restrict__ g_b, const float* __restrict__ be_b,
    const float* __restrict__ m_b, const float* __restrict__ v_b,
    const float* __restrict__ W1n,     // fp32 [64,64] next layer's W1 (unused if LAST)
    const int* __restrict__ batch,
    ushort* __restrict__ Ynext,        // bf16 [N,64]
    float* __restrict__ readout,       // fp32 [G,320]
    int layer_off)
{
    __shared__ __align__(16) ushort W2t[64 * 72];     // W2^T [c][k]
    __shared__ __align__(16) ushort W1nt[64 * 72];    // W1next^T [c][k]
    __shared__ __align__(16) ushort zA[4][16 * 72];   // per-wave tile [r][k]
    __shared__ float2 bnA[64], bnB[64];
    __shared__ __align__(16) int idxs[4][128];

    for (int e = threadIdx.x; e < 64 * 64; e += 256) {
        int c = e & 63, k = e >> 6;
        W2t[c * 72 + k] = f2bf(W2[k * 64 + c]);
        if constexpr (!LAST) W1nt[c * 72 + k] = f2bf(W1n[k * 64 + c]);
    }
    if (threadIdx.x < 64) {
        int c = threadIdx.x;
        float sa = g_a[c] * rsqrtf(v_a[c] + 1e-5f);
        float sb = g_b[c] * rsqrtf(v_b[c] + 1e-5f);
        bnA[c] = make_float2(sa, be_a[c] + (b1[c] - m_a[c]) * sa);
        bnB[c] = make_float2(sb, be_b[c] + (b2[c] - m_b[c]) * sb);
    }
    const float eps_l = 1.0f + eps_arr[l];
    __syncthreads();

    const int lane = threadIdx.x & 63;
    const int wave = threadIdx.x >> 6;
    const int fr = lane & 15, fq = lane >> 4;
    ushort* zw = zA[wave];
    int* idw = idxs[wave];
    const float2 ba = bnA[lane];

    for (int grp = blockIdx.x; grp < NGRP; grp += gridDim.x) {
        const int base = grp * 64 + wave * 16;
        if (base >= NN) continue;      // NN%16==0: waves all-valid or all-idle

        // ---- phase 1: dual-row gather (2 rows in flight), v1 -> zw ----
        for (int i = 0; i < 16; i += 2) {
            const int rowA = base + i, rowB = base + i + 1;
            const int rsA = rowptr[rowA], reA = rowptr[rowA + 1];
            const int rsB = rowptr[rowB], reB = rowptr[rowB + 1];
            float accA = eps_l * bf2f(Y[(size_t)rowA * 64 + lane]);
            float accB = eps_l * bf2f(Y[(size_t)rowB * 64 + lane]);
            int ja = rsA, jb = rsB;
            while (ja < reA || jb < reB) {
                int cntA = reA - ja; cntA = cntA > 64 ? 64 : (cntA < 0 ? 0 : cntA);
                int cntB = reB - jb; cntB = cntB > 64 ? 64 : (cntB < 0 ? 0 : cntB);
                if (lane < cntA) idw[lane] = col[ja + lane];
                if (lane < cntB) idw[64 + lane] = col[jb + lane];
                int ta = 0, tb = 0;
                for (; ta + 4 <= cntA && tb + 4 <= cntB; ta += 4, tb += 4) {
                    int4 a4 = *(const int4*)&idw[ta];
                    int4 b4 = *(const int4*)&idw[64 + tb];
                    float va0 = bf2f(Y[(size_t)a4.x * 64 + lane]);
                    float va1 = bf2f(Y[(size_t)a4.y * 64 + lane]);
                    float va2 = bf2f(Y[(size_t)a4.z * 64 + lane]);
                    float va3 = bf2f(Y[(size_t)a4.w * 64 + lane]);
                    float vb0 = bf2f(Y[(size_t)b4.x * 64 + lane]);
                    float vb1 = bf2f(Y[(size_t)b4.y * 64 + lane]);
                    float vb2 = bf2f(Y[(size_t)b4.z * 64 + lane]);
                    float vb3 = bf2f(Y[(size_t)b4.w * 64 + lane]);
                    accA += (va0 + va1) + (va2 + va3);
                    accB += (vb0 + vb1) + (vb2 + vb3);
                }
                for (; ta + 4 <= cntA; ta += 4) {
                    int4 a4 = *(const int4*)&idw[ta];
                    float v0 = bf2f(Y[(size_t)a4.x * 64 + lane]);
                    float v1 = bf2f(Y[(size_t)a4.y * 64 + lane]);
                    float v2 = bf2f(Y[(size_t)a4.z * 64 + lane]);
                    float v3 = bf2f(Y[(size_t)a4.w * 64 + lane]);
                    accA += (v0 + v1) + (v2 + v3);
                }
                for (; ta < cntA; ++ta) accA += bf2f(Y[(size_t)idw[ta] * 64 + lane]);
                for (; tb + 4 <= cntB; tb += 4) {
                    int4 b4 = *(const int4*)&idw[64 + tb];
                    float v0 = bf2f(Y[(size_t)b4.x * 64 + lane]);
                    float v1 = bf2f(Y[(size_t)b4.y * 64 + lane]);
                    float v2 = bf2f(Y[(size_t)b4.z * 64 + lane]);
                    float v3 = bf2f(Y[(size_t)b4.w * 64 + lane]);
                    accB += (v0 + v1) + (v2 + v3);
                }
                for (; tb < cntB; ++tb) accB += bf2f(Y[(size_t)idw[64 + tb] * 64 + lane]);
                ja += cntA; jb += cntB;
            }
            zw[i * 72 + lane]       = f2bf(fmaxf(accA * ba.x + ba.y, 0.f));
            zw[(i + 1) * 72 + lane] = f2bf(fmaxf(accB * ba.x + ba.y, 0.f));
        }

        // ---- phase 2: v2 = relu(bnB(v1 @ W2)) -> zw (A-frags hoisted before writes) ----
        short8 a2[2];
        a2[0] = *(const short8*)&zw[fr * 72 + fq * 8];
        a2[1] = *(const short8*)&zw[fr * 72 + 32 + fq * 8];
        #pragma unroll
        for (int t = 0; t < 4; ++t) {
            f32x4 acc = {0.f, 0.f, 0.f, 0.f};
            short8 bw0 = *(const short8*)&W2t[(t * 16 + fr) * 72 + fq * 8];
            short8 bw1 = *(const short8*)&W2t[(t * 16 + fr) * 72 + 32 + fq * 8];
            acc = __builtin_amdgcn_mfma_f32_16x16x32_bf16(a2[0], bw0, acc, 0, 0, 0);
            acc = __builtin_amdgcn_mfma_f32_16x16x32_bf16(a2[1], bw1, acc, 0, 0, 0);
            float2 bn = bnB[t * 16 + fr];
            #pragma unroll
            for (int r = 0; r < 4; ++r) {
                float v = fmaxf(acc[r] * bn.x + bn.y, 0.f);
                zw[(fq * 4 + r) * 72 + t * 16 + fr] = f2bf(v);
            }
        }

        // ---- phase 3: run-length-reduced readout atomics (v2 rows in zw) ----
        {
            int curg = batch[base];
            float racc = 0.f;
            #pragma unroll 4
            for (int i = 0; i < 16; ++i) {
                const float v = bf2f(zw[i * 72 + lane]);
                const int g = batch[base + i];
                if (g != curg) {   // wave-uniform (batch sorted)
                    unsafeAtomicAdd(readout + (size_t)curg * RCOLS + layer_off + lane, racc);
                    curg = g;
                    racc = v;
                } else {
                    racc += v;
                }
            }
            unsafeAtomicAdd(readout + (size_t)curg * RCOLS + layer_off + lane, racc);
        }

        // ---- phase 4: Ynext = v2 @ W1next; coalesced row stores ----
        if constexpr (!LAST) {
            short8 a3[2];
            a3[0] = *(const short8*)&zw[fr * 72 + fq * 8];
            a3[1] = *(const short8*)&zw[fr * 72 + 32 + fq * 8];
            #pragma unroll
            for (int t = 0; t < 4; ++t) {
                f32x4 acc = {0.f, 0.f, 0.f, 0.f};
                short8 bw0 = *(const short8*)&W1nt[(t * 16 + fr) * 72 + fq * 8];
                short8 bw1 = *(const short8*)&W1nt[(t * 16 + fr) * 72 + 32 + fq * 8];
                acc = __builtin_amdgcn_mfma_f32_16x16x32_bf16(a3[0], bw0, acc, 0, 0, 0);
                acc = __builtin_amdgcn_mfma_f32_16x16x32_bf16(a3[1], bw1, acc, 0, 0, 0);
                #pragma unroll
                for (int r = 0; r < 4; ++r)
                    zw[(fq * 4 + r) * 72 + t * 16 + fr] = f2bf(acc[r]);
            }
            #pragma unroll 4
            for (int i = 0; i < 16; ++i)
                Ynext[(size_t)(base + i) * 64 + lane] = zw[i * 72 + lane];
        }
    }
}

// ---------------- final graph-level GEMM: [G,320] @ [320,16] + bc ----------------
__global__ __launch_bounds__(256) void final_gemm(
    const float* __restrict__ R, const float* __restrict__ Wc,
    const float* __restrict__ bc, float* __restrict__ out)
{
    const int tid = blockIdx.x * 256 + threadIdx.x;
    if (tid >= GG * OUTC) return;
    const int g = tid >> 4;
    const int o = tid & 15;
    float acc = bc[o];
    const float* r = R + (size_t)g * RCOLS;
    #pragma unroll 8
    for (int k = 0; k < RCOLS; ++k)
        acc += r[k] * Wc[k * OUTC + o];
    out[tid] = acc;
}

extern "C" void kernel_launch(void* const* d_in, const int* in_sizes, int n_in,
                              void* d_out, int out_size, void* d_ws, size_t ws_size,
                              hipStream_t stream)
{
    const float* x    = (const float*)d_in[0];
    const int*   ei   = (const int*)d_in[1];
    const int*   batch= (const int*)d_in[2];
    const float* eps  = (const float*)d_in[3];
    const float* W1_0 = (const float*)d_in[4];
    const float* b1_0 = (const float*)d_in[5];
    const float* W1_r = (const float*)d_in[6];
    const float* b1_r = (const float*)d_in[7];
    const float* g_a  = (const float*)d_in[8];
    const float* be_a = (const float*)d_in[9];
    const float* m_a  = (const float*)d_in[10];
    const float* v_a  = (const float*)d_in[11];
    const float* W2   = (const float*)d_in[12];
    const float* b2   = (const float*)d_in[13];
    const float* g_b  = (const float*)d_in[14];
    const float* be_b = (const float*)d_in[15];
    const float* m_b  = (const float*)d_in[16];
    const float* v_b  = (const float*)d_in[17];
    const float* Wc   = (const float*)d_in[18];
    const float* bc   = (const float*)d_in[19];
    float* out = (float*)d_out;

    const int* src = ei;
    const int* dst = ei + EE;

    // workspace layout (bytes)
    char* ws = (char*)d_ws;
    int*    rowptr  = (int*)(ws);                        // 400KB+
    int*    deg     = (int*)(ws + 524288);
    int*    cursor  = (int*)(ws + 1048576);
    int*    bsums   = (int*)(ws + 1441792);
    int*    boffs   = (int*)(ws + 1507328);
    int*    col     = (int*)(ws + 1572864);              // 6.4MB
    ushort* y_a     = (ushort*)(ws + 8388608);           // N*64*2 = 12.8MB
    ushort* y_b     = (ushort*)(ws + 21233664);          // 12.8MB
    float*  readout = (float*)(ws + 34078720);           // 640KB

    hipMemsetAsync(deg, 0, (size_t)NN * 4, stream);
    hipMemsetAsync(readout, 0, (size_t)GG * RCOLS * 4, stream);

    hist_kernel<<<2048, 256, 0, stream>>>(dst, deg);
    ingemm_kernel<<<NGRP, 256, 0, stream>>>(x, W1_0, y_a);   // y0 = x @ W1_0
    scan1_kernel<<<NBLK, 256, 0, stream>>>(deg, bsums);
    scan2_kernel<<<1, 512, 0, stream>>>(bsums, boffs, rowptr);
    scan3_kernel<<<NBLK, 256, 0, stream>>>(deg, boffs, rowptr, cursor);
    fill_kernel<<<2048, 256, 0, stream>>>(src, dst, cursor, col);

    ushort* y_cur = y_a;
    ushort* y_nxt = y_b;

    for (int l = 0; l < LL; ++l) {
        const float* b1 = (l == 0) ? b1_0 : (b1_r + (size_t)(l - 1) * 64);
        const float* W1n = (l < LL - 1) ? (W1_r + (size_t)l * 64 * 64) : W1_r;
        const int off = l * 64;
        if (l < LL - 1) {
            gin_layer_kernel<false><<<NGRP, 256, 0, stream>>>(
                y_cur, rowptr, col, eps, l, b1,
                W2 + (size_t)l * 64 * 64, b2 + off,
                g_a + off, be_a + off, m_a + off, v_a + off,
                g_b + off, be_b + off, m_b + off, v_b + off,
                W1n, batch, y_nxt, readout, off);
        } else {
            gin_layer_kernel<true><<<NGRP, 256, 0, stream>>>(
                y_cur, rowptr, col, eps, l, b1,
                W2 + (size_t)l * 64 * 64, b2 + off,
                g_a + off, be_a + off, m_a + off, v_a + off,
                g_b + off, be_b + off, m_b + off, v_b + off,
                W1n, batch, y_nxt, readout, off);
        }
        ushort* t = y_cur; y_cur = y_nxt; y_nxt = t;
    }

    final_gemm<<<(GG * OUTC + 255) / 256, 256, 0, stream>>>(readout, Wc, bc, out);
}

// Round 7
// 480.589 us; speedup vs baseline: 18.0621x; 1.2482x over previous
//
#include <hip/hip_runtime.h>

#define NN 100000
#define EE 1600000
#define GG 512
#define LL 5
#define HID 64
#define RCOLS (HID*LL)   // 320
#define OUTC 16
#define NGRP ((NN + 63) / 64)     // 1563
#define NBUCK ((NN + 255) / 256)  // 391 buckets of 256 nodes

typedef unsigned int uint;
typedef unsigned short ushort;
typedef __attribute__((ext_vector_type(8))) short short8;
typedef __attribute__((ext_vector_type(4))) float f32x4;

__device__ __forceinline__ float bf2f(ushort u) {
    return __uint_as_float(((uint)u) << 16);
}
__device__ __forceinline__ ushort f2bf(float f) {
    uint u = __float_as_uint(f);
    u = (u + 0x7fffu + ((u >> 16) & 1u)) >> 16;   // round-to-nearest-even
    return (ushort)u;
}

// ================= bucketed CSR build (all scatters LDS/L2-local) =================
// bucket(d) = d >> 8 (256 nodes per bucket, 391 buckets)

__global__ __launch_bounds__(256) void binhist_kernel(
    const int* __restrict__ dst, int* __restrict__ bcnt)
{
    __shared__ int h[NBUCK];
    for (int b = threadIdx.x; b < NBUCK; b += 256) h[b] = 0;
    __syncthreads();
    for (int e = blockIdx.x * 256 + threadIdx.x; e < EE; e += gridDim.x * 256)
        atomicAdd(&h[dst[e] >> 8], 1);
    __syncthreads();
    for (int b = threadIdx.x; b < NBUCK; b += 256) {
        int c = h[b];
        if (c) atomicAdd(&bcnt[b], c);
    }
}

__global__ __launch_bounds__(512) void binscan_kernel(
    const int* __restrict__ bcnt, int* __restrict__ bbase, int* __restrict__ bcur)
{
    __shared__ int s[512];
    const int t = threadIdx.x;
    int v = (t < NBUCK) ? bcnt[t] : 0;
    s[t] = v;
    __syncthreads();
    int val = v;
    for (int off = 1; off < 512; off <<= 1) {
        int other = (t >= off) ? s[t - off] : 0;
        __syncthreads();
        val += other;
        s[t] = val;
        __syncthreads();
    }
    if (t < NBUCK) { bbase[t] = val - v; bcur[t] = val - v; }
    if (t == 0) bbase[NBUCK] = EE;
}

// bin edges by bucket; per-block bulk reservation -> append-style writes
__global__ __launch_bounds__(256) void binfill_kernel(
    const int* __restrict__ src, const int* __restrict__ dst,
    int* __restrict__ bcur, uint* __restrict__ bin)
{
    __shared__ int hcnt[NBUCK], hbase[NBUCK];
    const int tid = threadIdx.x;
    for (int b = tid; b < NBUCK; b += 256) hcnt[b] = 0;
    __syncthreads();
    const int chunk = (EE + gridDim.x - 1) / gridDim.x;
    const int e0 = blockIdx.x * chunk;
    const int e1 = (e0 + chunk < EE) ? e0 + chunk : EE;
    for (int e = e0 + tid; e < e1; e += 256)
        atomicAdd(&hcnt[dst[e] >> 8], 1);
    __syncthreads();
    for (int b = tid; b < NBUCK; b += 256) {
        int c = hcnt[b];
        hbase[b] = c ? atomicAdd(&bcur[b], c) : 0;
        hcnt[b] = 0;
    }
    __syncthreads();
    for (int e = e0 + tid; e < e1; e += 256) {
        int d = dst[e];
        int b = d >> 8;
        int off = atomicAdd(&hcnt[b], 1);
        bin[hbase[b] + off] = ((uint)src[e] << 8) | (uint)(d & 255);   // src<2^24
    }
}

// per-bucket: LDS hist(256 nodes) -> LDS scan -> rowptr; LDS-cursor scatter -> col
__global__ __launch_bounds__(256) void bucket_csr_kernel(
    const uint* __restrict__ bin, const int* __restrict__ bbase,
    int* __restrict__ rowptr, int* __restrict__ col)
{
    __shared__ int h[256], s[256];
    const int b = blockIdx.x;
    const int tid = threadIdx.x;
    const int base = bbase[b];
    const int cnt = bbase[b + 1] - base;
    h[tid] = 0;
    __syncthreads();
    for (int i = tid; i < cnt; i += 256)
        atomicAdd(&h[bin[base + i] & 255], 1);
    __syncthreads();
    const int own = h[tid];
    s[tid] = own;
    __syncthreads();
    int val = own;
    for (int off = 1; off < 256; off <<= 1) {
        int other = (tid >= off) ? s[tid - off] : 0;
        __syncthreads();
        val += other;
        s[tid] = val;
        __syncthreads();
    }
    const int excl = val - own;
    const int node = b * 256 + tid;
    if (node < NN) rowptr[node] = base + excl;
    h[tid] = base + excl;      // per-node cursor
    __syncthreads();
    for (int i = tid; i < cnt; i += 256) {
        uint w = bin[base + i];
        int p = atomicAdd(&h[w & 255], 1);
        col[p] = (int)(w >> 8);
    }
    if (b == 0 && tid == 0) rowptr[NN] = EE;
}

// ---------------- y0 = x @ W1_0  (fp32 [N,128] @ [128,64] -> bf16 [N,64]) ----------------
// mfma(A-frag,B-frag) = A·B^T, frags k-contiguous per lane; C/D col=lane&15, row=(lane>>4)*4+r.
__global__ __launch_bounds__(256) void ingemm_kernel(
    const float* __restrict__ x, const float* __restrict__ W1,
    ushort* __restrict__ Y0)
{
    __shared__ __align__(16) ushort W1t[64 * 136];   // W1^T [c][k], k=0..127, pad 136
    __shared__ __align__(16) ushort zA[4][16 * 72];

    for (int e = threadIdx.x; e < 64 * 128; e += 256) {
        int c = e & 63, k = e >> 6;
        W1t[c * 136 + k] = f2bf(W1[k * 64 + c]);
    }
    __syncthreads();

    const int lane = threadIdx.x & 63;
    const int wave = threadIdx.x >> 6;
    const int fr = lane & 15, fq = lane >> 4;
    ushort* zw = zA[wave];

    for (int grp = blockIdx.x; grp < NGRP; grp += gridDim.x) {
        const int base = grp * 64 + wave * 16;
        if (base >= NN) continue;

        short8 az[4];
        #pragma unroll
        for (int h = 0; h < 4; ++h) {
            const float* xp = x + (size_t)(base + fr) * 128 + h * 32 + fq * 8;
            float4 f0 = *(const float4*)xp;
            float4 f1 = *(const float4*)(xp + 4);
            short8 a;
            a[0] = (short)f2bf(f0.x); a[1] = (short)f2bf(f0.y);
            a[2] = (short)f2bf(f0.z); a[3] = (short)f2bf(f0.w);
            a[4] = (short)f2bf(f1.x); a[5] = (short)f2bf(f1.y);
            a[6] = (short)f2bf(f1.z); a[7] = (short)f2bf(f1.w);
            az[h] = a;
        }
        #pragma unroll
        for (int t = 0; t < 4; ++t) {
            f32x4 acc = {0.f, 0.f, 0.f, 0.f};
            #pragma unroll
            for (int h = 0; h < 4; ++h) {
                short8 bw = *(const short8*)&W1t[(t * 16 + fr) * 136 + h * 32 + fq * 8];
                acc = __builtin_amdgcn_mfma_f32_16x16x32_bf16(az[h], bw, acc, 0, 0, 0);
            }
            #pragma unroll
            for (int r = 0; r < 4; ++r)
                zw[(fq * 4 + r) * 72 + t * 16 + fr] = f2bf(acc[r]);
        }
        #pragma unroll 4
        for (int i = 0; i < 16; ++i)
            Y0[(size_t)(base + i) * 64 + lane] = zw[i * 72 + lane];
    }
}

// ------- fused layer on Y = h@W1 (bf16 [N,64]):
//   gather t = (1+eps)*Y[row] + sum Y[neigh]  (this IS z@W1, linear-commute)
//   v1 = relu(t*saA + shA); v2 = relu((v1@W2)*sbB + shB)
//   readout[g] += v2 ; if !LAST: Ynext = v2 @ W1next
template<bool LAST>
__global__ __launch_bounds__(256, 5) void gin_layer_kernel(
    const ushort* __restrict__ Y,      // bf16 [N,64]
    const int* __restrict__ rowptr, const int* __restrict__ col,
    const float* __restrict__ eps_arr, int l,
    const float* __restrict__ b1,
    const float* __restrict__ W2, const float* __restrict__ b2,   // fp32 [64,64],[64]
    const float* __restrict__ g_a, const float* __restrict__ be_a,
    const float* __restrict__ m_a, const float* __restrict__ v_a,
    const float* __restrict__ g_b, const float* __restrict__ be_b,
    const float* __restrict__ m_b, const float* __restrict__ v_b,
    const float* __restrict__ W1n,     // fp32 [64,64] next layer's W1 (unused if LAST)
    const int* __restrict__ batch,
    ushort* __restrict__ Ynext,        // bf16 [N,64]
    float* __restrict__ readout,       // fp32 [G,320]
    int layer_off)
{
    __shared__ __align__(16) ushort W2t[64 * 72];     // W2^T [c][k]
    __shared__ __align__(16) ushort W1nt[64 * 72];    // W1next^T [c][k]
    __shared__ __align__(16) ushort zA[4][16 * 72];   // per-wave tile [r][k]
    __shared__ float2 bnA[64], bnB[64];
    __shared__ __align__(16) int idxs[4][128];

    for (int e = threadIdx.x; e < 64 * 64; e += 256) {
        int c = e & 63, k = e >> 6;
        W2t[c * 72 + k] = f2bf(W2[k * 64 + c]);
        if constexpr (!LAST) W1nt[c * 72 + k] = f2bf(W1n[k * 64 + c]);
    }
    if (threadIdx.x < 64) {
        int c = threadIdx.x;
        float sa = g_a[c] * rsqrtf(v_a[c] + 1e-5f);
        float sb = g_b[c] * rsqrtf(v_b[c] + 1e-5f);
        bnA[c] = make_float2(sa, be_a[c] + (b1[c] - m_a[c]) * sa);
        bnB[c] = make_float2(sb, be_b[c] + (b2[c] - m_b[c]) * sb);
    }
    const float eps_l = 1.0f + eps_arr[l];
    __syncthreads();

    const int lane = threadIdx.x & 63;
    const int wave = threadIdx.x >> 6;
    const int fr = lane & 15, fq = lane >> 4;
    ushort* zw = zA[wave];
    int* idw = idxs[wave];
    const float2 ba = bnA[lane];

    for (int grp = blockIdx.x; grp < NGRP; grp += gridDim.x) {
        const int base = grp * 64 + wave * 16;
        if (base >= NN) continue;      // NN%16==0: waves all-valid or all-idle

        // ---- phase 1: dual-row gather (2 rows in flight), v1 -> zw ----
        for (int i = 0; i < 16; i += 2) {
            const int rowA = base + i, rowB = base + i + 1;
            const int rsA = rowptr[rowA], reA = rowptr[rowA + 1];
            const int rsB = rowptr[rowB], reB = rowptr[rowB + 1];
            float accA = eps_l * bf2f(Y[(size_t)rowA * 64 + lane]);
            float accB = eps_l * bf2f(Y[(size_t)rowB * 64 + lane]);
            int ja = rsA, jb = rsB;
            while (ja < reA || jb < reB) {
                int cntA = reA - ja; cntA = cntA > 64 ? 64 : (cntA < 0 ? 0 : cntA);
                int cntB = reB - jb; cntB = cntB > 64 ? 64 : (cntB < 0 ? 0 : cntB);
                if (lane < cntA) idw[lane] = col[ja + lane];
                if (lane < cntB) idw[64 + lane] = col[jb + lane];
                int ta = 0, tb = 0;
                for (; ta + 4 <= cntA && tb + 4 <= cntB; ta += 4, tb += 4) {
                    int4 a4 = *(const int4*)&idw[ta];
                    int4 b4 = *(const int4*)&idw[64 + tb];
                    float va0 = bf2f(Y[(size_t)a4.x * 64 + lane]);
                    float va1 = bf2f(Y[(size_t)a4.y * 64 + lane]);
                    float va2 = bf2f(Y[(size_t)a4.z * 64 + lane]);
                    float va3 = bf2f(Y[(size_t)a4.w * 64 + lane]);
                    float vb0 = bf2f(Y[(size_t)b4.x * 64 + lane]);
                    float vb1 = bf2f(Y[(size_t)b4.y * 64 + lane]);
                    float vb2 = bf2f(Y[(size_t)b4.z * 64 + lane]);
                    float vb3 = bf2f(Y[(size_t)b4.w * 64 + lane]);
                    accA += (va0 + va1) + (va2 + va3);
                    accB += (vb0 + vb1) + (vb2 + vb3);
                }
                for (; ta + 4 <= cntA; ta += 4) {
                    int4 a4 = *(const int4*)&idw[ta];
                    float v0 = bf2f(Y[(size_t)a4.x * 64 + lane]);
                    float v1 = bf2f(Y[(size_t)a4.y * 64 + lane]);
                    float v2 = bf2f(Y[(size_t)a4.z * 64 + lane]);
                    float v3 = bf2f(Y[(size_t)a4.w * 64 + lane]);
                    accA += (v0 + v1) + (v2 + v3);
                }
                for (; ta < cntA; ++ta) accA += bf2f(Y[(size_t)idw[ta] * 64 + lane]);
                for (; tb + 4 <= cntB; tb += 4) {
                    int4 b4 = *(const int4*)&idw[64 + tb];
                    float v0 = bf2f(Y[(size_t)b4.x * 64 + lane]);
                    float v1 = bf2f(Y[(size_t)b4.y * 64 + lane]);
                    float v2 = bf2f(Y[(size_t)b4.z * 64 + lane]);
                    float v3 = bf2f(Y[(size_t)b4.w * 64 + lane]);
                    accB += (v0 + v1) + (v2 + v3);
                }
                for (; tb < cntB; ++tb) accB += bf2f(Y[(size_t)idw[64 + tb] * 64 + lane]);
                ja += cntA; jb += cntB;
            }
            zw[i * 72 + lane]       = f2bf(fmaxf(accA * ba.x + ba.y, 0.f));
            zw[(i + 1) * 72 + lane] = f2bf(fmaxf(accB * ba.x + ba.y, 0.f));
        }

        // ---- phase 2: v2 = relu(bnB(v1 @ W2)) -> zw ----
        short8 a2[2];
        a2[0] = *(const short8*)&zw[fr * 72 + fq * 8];
        a2[1] = *(const short8*)&zw[fr * 72 + 32 + fq * 8];
        #pragma unroll
        for (int t = 0; t < 4; ++t) {
            f32x4 acc = {0.f, 0.f, 0.f, 0.f};
            short8 bw0 = *(const short8*)&W2t[(t * 16 + fr) * 72 + fq * 8];
            short8 bw1 = *(const short8*)&W2t[(t * 16 + fr) * 72 + 32 + fq * 8];
            acc = __builtin_amdgcn_mfma_f32_16x16x32_bf16(a2[0], bw0, acc, 0, 0, 0);
            acc = __builtin_amdgcn_mfma_f32_16x16x32_bf16(a2[1], bw1, acc, 0, 0, 0);
            float2 bn = bnB[t * 16 + fr];
            #pragma unroll
            for (int r = 0; r < 4; ++r) {
                float v = fmaxf(acc[r] * bn.x + bn.y, 0.f);
                zw[(fq * 4 + r) * 72 + t * 16 + fr] = f2bf(v);
            }
        }

        // ---- phase 3: run-length-reduced readout atomics (v2 rows in zw) ----
        {
            int curg = batch[base];
            float racc = 0.f;
            #pragma unroll 4
            for (int i = 0; i < 16; ++i) {
                const float v = bf2f(zw[i * 72 + lane]);
                const int g = batch[base + i];
                if (g != curg) {   // wave-uniform (batch sorted)
                    unsafeAtomicAdd(readout + (size_t)curg * RCOLS + layer_off + lane, racc);
                    curg = g;
                    racc = v;
                } else {
                    racc += v;
                }
            }
            unsafeAtomicAdd(readout + (size_t)curg * RCOLS + layer_off + lane, racc);
        }

        // ---- phase 4: Ynext = v2 @ W1next; coalesced row stores ----
        if constexpr (!LAST) {
            short8 a3[2];
            a3[0] = *(const short8*)&zw[fr * 72 + fq * 8];
            a3[1] = *(const short8*)&zw[fr * 72 + 32 + fq * 8];
            #pragma unroll
            for (int t = 0; t < 4; ++t) {
                f32x4 acc = {0.f, 0.f, 0.f, 0.f};
                short8 bw0 = *(const short8*)&W1nt[(t * 16 + fr) * 72 + fq * 8];
                short8 bw1 = *(const short8*)&W1nt[(t * 16 + fr) * 72 + 32 + fq * 8];
                acc = __builtin_amdgcn_mfma_f32_16x16x32_bf16(a3[0], bw0, acc, 0, 0, 0);
                acc = __builtin_amdgcn_mfma_f32_16x16x32_bf16(a3[1], bw1, acc, 0, 0, 0);
                #pragma unroll
                for (int r = 0; r < 4; ++r)
                    zw[(fq * 4 + r) * 72 + t * 16 + fr] = f2bf(acc[r]);
            }
            #pragma unroll 4
            for (int i = 0; i < 16; ++i)
                Ynext[(size_t)(base + i) * 64 + lane] = zw[i * 72 + lane];
        }
    }
}

// ---------------- final graph-level GEMM: [G,320] @ [320,16] + bc ----------------
__global__ __launch_bounds__(256) void final_gemm(
    const float* __restrict__ R, const float* __restrict__ Wc,
    const float* __restrict__ bc, float* __restrict__ out)
{
    const int tid = blockIdx.x * 256 + threadIdx.x;
    if (tid >= GG * OUTC) return;
    const int g = tid >> 4;
    const int o = tid & 15;
    float acc = bc[o];
    const float* r = R + (size_t)g * RCOLS;
    #pragma unroll 8
    for (int k = 0; k < RCOLS; ++k)
        acc += r[k] * Wc[k * OUTC + o];
    out[tid] = acc;
}

extern "C" void kernel_launch(void* const* d_in, const int* in_sizes, int n_in,
                              void* d_out, int out_size, void* d_ws, size_t ws_size,
                              hipStream_t stream)
{
    const float* x    = (const float*)d_in[0];
    const int*   ei   = (const int*)d_in[1];
    const int*   batch= (const int*)d_in[2];
    const float* eps  = (const float*)d_in[3];
    const float* W1_0 = (const float*)d_in[4];
    const float* b1_0 = (const float*)d_in[5];
    const float* W1_r = (const float*)d_in[6];
    const float* b1_r = (const float*)d_in[7];
    const float* g_a  = (const float*)d_in[8];
    const float* be_a = (const float*)d_in[9];
    const float* m_a  = (const float*)d_in[10];
    const float* v_a  = (const float*)d_in[11];
    const float* W2   = (const float*)d_in[12];
    const float* b2   = (const float*)d_in[13];
    const float* g_b  = (const float*)d_in[14];
    const float* be_b = (const float*)d_in[15];
    const float* m_b  = (const float*)d_in[16];
    const float* v_b  = (const float*)d_in[17];
    const float* Wc   = (const float*)d_in[18];
    const float* bc   = (const float*)d_in[19];
    float* out = (float*)d_out;

    const int* src = ei;
    const int* dst = ei + EE;

    // workspace layout (bytes)
    char* ws = (char*)d_ws;
    int*    rowptr  = (int*)(ws);                        // (N+1)*4
    int*    bcnt    = (int*)(ws + 524288);               // NBUCK
    int*    bbase   = (int*)(ws + 528384);               // NBUCK+1
    int*    bcur    = (int*)(ws + 532480);               // NBUCK
    int*    col     = (int*)(ws + 1048576);              // E*4 = 6.4MB
    uint*   bin     = (uint*)(ws + 7602176);             // E*4 = 6.4MB
    ushort* y_a     = (ushort*)(ws + 14155776);          // N*64*2 = 12.8MB
    ushort* y_b     = (ushort*)(ws + 26955776);          // 12.8MB
    float*  readout = (float*)(ws + 39755776);           // 640KB

    hipMemsetAsync(bcnt, 0, (size_t)NBUCK * 4, stream);
    hipMemsetAsync(readout, 0, (size_t)GG * RCOLS * 4, stream);

    binhist_kernel<<<256, 256, 0, stream>>>(dst, bcnt);
    ingemm_kernel<<<NGRP, 256, 0, stream>>>(x, W1_0, y_a);   // y0 = x @ W1_0
    binscan_kernel<<<1, 512, 0, stream>>>(bcnt, bbase, bcur);
    binfill_kernel<<<128, 256, 0, stream>>>(src, dst, bcur, bin);
    bucket_csr_kernel<<<NBUCK, 256, 0, stream>>>(bin, bbase, rowptr, col);

    ushort* y_cur = y_a;
    ushort* y_nxt = y_b;

    for (int l = 0; l < LL; ++l) {
        const float* b1 = (l == 0) ? b1_0 : (b1_r + (size_t)(l - 1) * 64);
        const float* W1n = (l < LL - 1) ? (W1_r + (size_t)l * 64 * 64) : W1_r;
        const int off = l * 64;
        if (l < LL - 1) {
            gin_layer_kernel<false><<<NGRP, 256, 0, stream>>>(
                y_cur, rowptr, col, eps, l, b1,
                W2 + (size_t)l * 64 * 64, b2 + off,
                g_a + off, be_a + off, m_a + off, v_a + off,
                g_b + off, be_b + off, m_b + off, v_b + off,
                W1n, batch, y_nxt, readout, off);
        } else {
            gin_layer_kernel<true><<<NGRP, 256, 0, stream>>>(
                y_cur, rowptr, col, eps, l, b1,
                W2 + (size_t)l * 64 * 64, b2 + off,
                g_a + off, be_a + off, m_a + off, v_a + off,
                g_b + off, be_b + off, m_b + off, v_b + off,
                W1n, batch, y_nxt, readout, off);
        }
        ushort* t = y_cur; y_cur = y_nxt; y_nxt = t;
    }

    final_gemm<<<(GG * OUTC + 255) / 256, 256, 0, stream>>>(readout, Wc, bc, out);
}

// Round 8
// 381.158 us; speedup vs baseline: 22.7739x; 1.2609x over previous
//
#include <hip/hip_runtime.h>

#define NN 100000
#define EE 1600000
#define GG 512
#define LL 5
#define HID 64
#define RCOLS (HID*LL)   // 320
#define OUTC 16
#define NGRP ((NN + 63) / 64)     // 1563
#define NBUCK ((NN + 255) / 256)  // 391 buckets of 256 nodes

typedef unsigned int uint;
typedef unsigned short ushort;
typedef __attribute__((ext_vector_type(8))) short short8;
typedef __attribute__((ext_vector_type(4))) float f32x4;

__device__ __forceinline__ float bf2f(ushort u) {
    return __uint_as_float(((uint)u) << 16);
}
__device__ __forceinline__ ushort f2bf(float f) {
    uint u = __float_as_uint(f);
    u = (u + 0x7fffu + ((u >> 16) & 1u)) >> 16;   // round-to-nearest-even
    return (ushort)u;
}
__device__ __forceinline__ uint pack2(float a, float b) {
    return (uint)f2bf(a) | ((uint)f2bf(b) << 16);
}
__device__ __forceinline__ float lo16(uint p) { return __uint_as_float(p << 16); }
__device__ __forceinline__ float hi16(uint p) { return __uint_as_float(p & 0xffff0000u); }

// ================= bucketed CSR build (all scatters LDS/L2-local) =================
__global__ __launch_bounds__(256) void binhist_kernel(
    const int* __restrict__ dst, int* __restrict__ bcnt)
{
    __shared__ int h[NBUCK];
    for (int b = threadIdx.x; b < NBUCK; b += 256) h[b] = 0;
    __syncthreads();
    for (int e = blockIdx.x * 256 + threadIdx.x; e < EE; e += gridDim.x * 256)
        atomicAdd(&h[dst[e] >> 8], 1);
    __syncthreads();
    for (int b = threadIdx.x; b < NBUCK; b += 256) {
        int c = h[b];
        if (c) atomicAdd(&bcnt[b], c);
    }
}

__global__ __launch_bounds__(512) void binscan_kernel(
    const int* __restrict__ bcnt, int* __restrict__ bbase, int* __restrict__ bcur)
{
    __shared__ int s[512];
    const int t = threadIdx.x;
    int v = (t < NBUCK) ? bcnt[t] : 0;
    s[t] = v;
    __syncthreads();
    int val = v;
    for (int off = 1; off < 512; off <<= 1) {
        int other = (t >= off) ? s[t - off] : 0;
        __syncthreads();
        val += other;
        s[t] = val;
        __syncthreads();
    }
    if (t < NBUCK) { bbase[t] = val - v; bcur[t] = val - v; }
    if (t == 0) bbase[NBUCK] = EE;
}

__global__ __launch_bounds__(256) void binfill_kernel(
    const int* __restrict__ src, const int* __restrict__ dst,
    int* __restrict__ bcur, uint* __restrict__ bin)
{
    __shared__ int hcnt[NBUCK], hbase[NBUCK];
    const int tid = threadIdx.x;
    for (int b = tid; b < NBUCK; b += 256) hcnt[b] = 0;
    __syncthreads();
    const int chunk = (EE + gridDim.x - 1) / gridDim.x;
    const int e0 = blockIdx.x * chunk;
    const int e1 = (e0 + chunk < EE) ? e0 + chunk : EE;
    for (int e = e0 + tid; e < e1; e += 256)
        atomicAdd(&hcnt[dst[e] >> 8], 1);
    __syncthreads();
    for (int b = tid; b < NBUCK; b += 256) {
        int c = hcnt[b];
        hbase[b] = c ? atomicAdd(&bcur[b], c) : 0;
        hcnt[b] = 0;
    }
    __syncthreads();
    for (int e = e0 + tid; e < e1; e += 256) {
        int d = dst[e];
        int b = d >> 8;
        int off = atomicAdd(&hcnt[b], 1);
        bin[hbase[b] + off] = ((uint)src[e] << 8) | (uint)(d & 255);   // src<2^24
    }
}

__global__ __launch_bounds__(256) void bucket_csr_kernel(
    const uint* __restrict__ bin, const int* __restrict__ bbase,
    int* __restrict__ rowptr, int* __restrict__ col)
{
    __shared__ int h[256], s[256];
    const int b = blockIdx.x;
    const int tid = threadIdx.x;
    const int base = bbase[b];
    const int cnt = bbase[b + 1] - base;
    h[tid] = 0;
    __syncthreads();
    for (int i = tid; i < cnt; i += 256)
        atomicAdd(&h[bin[base + i] & 255], 1);
    __syncthreads();
    const int own = h[tid];
    s[tid] = own;
    __syncthreads();
    int val = own;
    for (int off = 1; off < 256; off <<= 1) {
        int other = (tid >= off) ? s[tid - off] : 0;
        __syncthreads();
        val += other;
        s[tid] = val;
        __syncthreads();
    }
    const int excl = val - own;
    const int node = b * 256 + tid;
    if (node < NN) rowptr[node] = base + excl;
    h[tid] = base + excl;      // per-node cursor
    __syncthreads();
    for (int i = tid; i < cnt; i += 256) {
        uint w = bin[base + i];
        int p = atomicAdd(&h[w & 255], 1);
        col[p] = (int)(w >> 8);
    }
    if (b == 0 && tid == 0) rowptr[NN] = EE;
}

// -------- prep: transposed bf16 weights, [c][72] padded rows, L1-resident at use --------
__global__ __launch_bounds__(256) void prep_w_kernel(
    const float* __restrict__ W2, const float* __restrict__ W1_r,
    ushort* __restrict__ w2t, ushort* __restrict__ w1nt)
{
    const int i = blockIdx.x * 256 + threadIdx.x;
    if (i < 5 * 4096) {
        int l = i >> 12, r = i & 4095, k = r >> 6, c = r & 63;
        w2t[l * 4608 + c * 72 + k] = f2bf(W2[l * 4096 + k * 64 + c]);
    }
    if (i < 4 * 4096) {
        int l = i >> 12, r = i & 4095, k = r >> 6, c = r & 63;
        w1nt[l * 4608 + c * 72 + k] = f2bf(W1_r[l * 4096 + k * 64 + c]);
    }
}

// ---------------- y0 = x @ W1_0  (fp32 [N,128] @ [128,64] -> bf16 [N,64]) ----------------
// mfma(A-frag,B-frag) = A·B^T, frags k-contiguous per lane; C/D col=lane&15, row=(lane>>4)*4+r.
__global__ __launch_bounds__(256) void ingemm_kernel(
    const float* __restrict__ x, const float* __restrict__ W1,
    ushort* __restrict__ Y0)
{
    __shared__ __align__(16) ushort W1t[64 * 136];   // W1^T [c][k], k=0..127, pad 136
    __shared__ __align__(16) ushort zA[4][16 * 72];

    for (int e = threadIdx.x; e < 64 * 128; e += 256) {
        int c = e & 63, k = e >> 6;
        W1t[c * 136 + k] = f2bf(W1[k * 64 + c]);
    }
    __syncthreads();

    const int lane = threadIdx.x & 63;
    const int wave = threadIdx.x >> 6;
    const int fr = lane & 15, fq = lane >> 4;
    ushort* zw = zA[wave];

    for (int grp = blockIdx.x; grp < NGRP; grp += gridDim.x) {
        const int base = grp * 64 + wave * 16;
        if (base >= NN) continue;

        short8 az[4];
        #pragma unroll
        for (int h = 0; h < 4; ++h) {
            const float* xp = x + (size_t)(base + fr) * 128 + h * 32 + fq * 8;
            float4 f0 = *(const float4*)xp;
            float4 f1 = *(const float4*)(xp + 4);
            short8 a;
            a[0] = (short)f2bf(f0.x); a[1] = (short)f2bf(f0.y);
            a[2] = (short)f2bf(f0.z); a[3] = (short)f2bf(f0.w);
            a[4] = (short)f2bf(f1.x); a[5] = (short)f2bf(f1.y);
            a[6] = (short)f2bf(f1.z); a[7] = (short)f2bf(f1.w);
            az[h] = a;
        }
        #pragma unroll
        for (int t = 0; t < 4; ++t) {
            f32x4 acc = {0.f, 0.f, 0.f, 0.f};
            #pragma unroll
            for (int h = 0; h < 4; ++h) {
                short8 bw = *(const short8*)&W1t[(t * 16 + fr) * 136 + h * 32 + fq * 8];
                acc = __builtin_amdgcn_mfma_f32_16x16x32_bf16(az[h], bw, acc, 0, 0, 0);
            }
            #pragma unroll
            for (int r = 0; r < 4; ++r)
                zw[(fq * 4 + r) * 72 + t * 16 + fr] = f2bf(acc[r]);
        }
        #pragma unroll 4
        for (int i = 0; i < 16; ++i)
            Y0[(size_t)(base + i) * 64 + lane] = zw[i * 72 + lane];
    }
}

// ------- fused layer on Y = h@W1 (bf16 [NN+1,64], row NN == zeros):
//   gather t = (1+eps)*Y[row] + sum Y[neigh]   (linear-commute: this IS z@W1)
//   v1 = relu(t*sa+sh); v2 = relu((v1@W2)*sb+shb); pool; Ynext = v2 @ W1next
// Gather: 2 neighbor rows per dword load (lanes 0-31 row A-half, 32-63 row B-half),
// index pads -> row NN (zero, L1-resident) => branch-free unrolled loads.
template<bool LAST>
__global__ __launch_bounds__(256, 6) void gin_layer_kernel(
    const ushort* __restrict__ Y,
    const int* __restrict__ rowptr, const int* __restrict__ col,
    const float* __restrict__ eps_arr, int l,
    const float* __restrict__ b1,
    const ushort* __restrict__ w2t,    // bf16 [64][72] W2^T
    const float* __restrict__ b2,
    const float* __restrict__ g_a, const float* __restrict__ be_a,
    const float* __restrict__ m_a, const float* __restrict__ v_a,
    const float* __restrict__ g_b, const float* __restrict__ be_b,
    const float* __restrict__ m_b, const float* __restrict__ v_b,
    const ushort* __restrict__ w1nt,   // bf16 [64][72] W1next^T (unused if LAST)
    const int* __restrict__ batch,
    ushort* __restrict__ Ynext,
    float* __restrict__ readout,
    int layer_off)
{
    __shared__ __align__(16) ushort zA[4][16 * 72];   // per-wave tile [r][k]
    __shared__ float2 bnA[64], bnB[64];
    __shared__ __align__(16) int idxs[4][128];

    if (threadIdx.x < 64) {
        int c = threadIdx.x;
        float sa = g_a[c] * rsqrtf(v_a[c] + 1e-5f);
        float sb = g_b[c] * rsqrtf(v_b[c] + 1e-5f);
        bnA[c] = make_float2(sa, be_a[c] + (b1[c] - m_a[c]) * sa);
        bnB[c] = make_float2(sb, be_b[c] + (b2[c] - m_b[c]) * sb);
    }
    const float eps_l = 1.0f + eps_arr[l];
    __syncthreads();

    const int lane = threadIdx.x & 63;
    const int wave = threadIdx.x >> 6;
    const int fr = lane & 15, fq = lane >> 4;
    const int c2 = lane & 31;          // channel-pair id (channels 2c2, 2c2+1)
    ushort* zw = zA[wave];
    int* idw = idxs[wave];
    const float2 ba0 = bnA[2 * c2];
    const float2 ba1 = bnA[2 * c2 + 1];

    for (int grp = blockIdx.x; grp < NGRP; grp += gridDim.x) {
        const int base = grp * 64 + wave * 16;
        if (base >= NN) continue;      // NN%16==0: waves all-valid or all-idle

        // ---- phase 1: gather pairs of rows; 8 dword loads (16 neighbor rows) in flight ----
        for (int i = 0; i < 16; i += 2) {
            const int rowA = base + i, rowB = base + i + 1;
            int ja = rowptr[rowA];
            const int reA = rowptr[rowA + 1];
            int jb = reA;                       // rowB starts where rowA ends (contiguous)
            const int reB = rowptr[rowB + 1];
            float accAx = 0.f, accAy = 0.f, accBx = 0.f, accBy = 0.f;
            while (ja < reA || jb < reB) {
                int cntA = reA - ja; cntA = cntA > 64 ? 64 : (cntA < 0 ? 0 : cntA);
                int cntB = reB - jb; cntB = cntB > 64 ? 64 : (cntB < 0 ? 0 : cntB);
                {
                    int ia = ja + lane; ia = ia < EE ? ia : EE - 1;
                    int ib = jb + lane; ib = ib < EE ? ib : EE - 1;
                    int ca = col[ia], cb = col[ib];
                    idw[lane]      = (lane < cntA) ? ca : NN;
                    idw[64 + lane] = (lane < cntB) ? cb : NN;
                }
                const int niA = (cntA + 1) >> 1, niB = (cntB + 1) >> 1;
                const int nmax = niA > niB ? niA : niB;
                for (int t = 0; t < nmax; t += 4) {
                    uint wA[4], wB[4];
                    #pragma unroll
                    for (int u = 0; u < 4; ++u) {
                        int pa = 2 * (t + u) + (lane >> 5);        // 0..63 (pads -> NN)
                        int ra = idw[pa];
                        int rb = idw[64 + pa];
                        wA[u] = *(const uint*)&Y[(size_t)ra * 64 + c2 * 2];
                        wB[u] = *(const uint*)&Y[(size_t)rb * 64 + c2 * 2];
                    }
                    #pragma unroll
                    for (int u = 0; u < 4; ++u) {
                        accAx += lo16(wA[u]); accAy += hi16(wA[u]);
                        accBx += lo16(wB[u]); accBy += hi16(wB[u]);
                    }
                }
                ja += cntA; jb += cntB;
            }
            // combine halves (each half summed a disjoint subset of neighbors)
            accAx += __shfl_xor(accAx, 32); accAy += __shfl_xor(accAy, 32);
            accBx += __shfl_xor(accBx, 32); accBy += __shfl_xor(accBy, 32);
            uint wrA = *(const uint*)&Y[(size_t)rowA * 64 + c2 * 2];
            uint wrB = *(const uint*)&Y[(size_t)rowB * 64 + c2 * 2];
            accAx += eps_l * lo16(wrA); accAy += eps_l * hi16(wrA);
            accBx += eps_l * lo16(wrB); accBy += eps_l * hi16(wrB);
            float a0 = fmaxf(accAx * ba0.x + ba0.y, 0.f);
            float a1 = fmaxf(accAy * ba1.x + ba1.y, 0.f);
            float b0 = fmaxf(accBx * ba0.x + ba0.y, 0.f);
            float b1v = fmaxf(accBy * ba1.x + ba1.y, 0.f);
            if (lane < 32) {
                *(uint*)&zw[i * 72 + c2 * 2]       = pack2(a0, a1);
                *(uint*)&zw[(i + 1) * 72 + c2 * 2] = pack2(b0, b1v);
            }
        }

        // ---- phase 2: v2 = relu(bnB(v1 @ W2)) -> zw (B-frags from L1-resident global) ----
        short8 a2[2];
        a2[0] = *(const short8*)&zw[fr * 72 + fq * 8];
        a2[1] = *(const short8*)&zw[fr * 72 + 32 + fq * 8];
        #pragma unroll
        for (int t = 0; t < 4; ++t) {
            f32x4 acc = {0.f, 0.f, 0.f, 0.f};
            short8 bw0 = *(const short8*)&w2t[(t * 16 + fr) * 72 + fq * 8];
            short8 bw1 = *(const short8*)&w2t[(t * 16 + fr) * 72 + 32 + fq * 8];
            acc = __builtin_amdgcn_mfma_f32_16x16x32_bf16(a2[0], bw0, acc, 0, 0, 0);
            acc = __builtin_amdgcn_mfma_f32_16x16x32_bf16(a2[1], bw1, acc, 0, 0, 0);
            float2 bn = bnB[t * 16 + fr];
            #pragma unroll
            for (int r = 0; r < 4; ++r) {
                float v = fmaxf(acc[r] * bn.x + bn.y, 0.f);
                zw[(fq * 4 + r) * 72 + t * 16 + fr] = f2bf(v);
            }
        }

        // ---- phase 3: run-length-reduced readout atomics ----
        {
            int curg = batch[base];
            float racc = 0.f;
            #pragma unroll 4
            for (int i = 0; i < 16; ++i) {
                const float v = bf2f(zw[i * 72 + lane]);
                const int g = batch[base + i];
                if (g != curg) {   // wave-uniform (batch sorted)
                    unsafeAtomicAdd(readout + (size_t)curg * RCOLS + layer_off + lane, racc);
                    curg = g;
                    racc = v;
                } else {
                    racc += v;
                }
            }
            unsafeAtomicAdd(readout + (size_t)curg * RCOLS + layer_off + lane, racc);
        }

        // ---- phase 4: Ynext = v2 @ W1next; coalesced row stores ----
        if constexpr (!LAST) {
            short8 a3[2];
            a3[0] = *(const short8*)&zw[fr * 72 + fq * 8];
            a3[1] = *(const short8*)&zw[fr * 72 + 32 + fq * 8];
            #pragma unroll
            for (int t = 0; t < 4; ++t) {
                f32x4 acc = {0.f, 0.f, 0.f, 0.f};
                short8 bw0 = *(const short8*)&w1nt[(t * 16 + fr) * 72 + fq * 8];
                short8 bw1 = *(const short8*)&w1nt[(t * 16 + fr) * 72 + 32 + fq * 8];
                acc = __builtin_amdgcn_mfma_f32_16x16x32_bf16(a3[0], bw0, acc, 0, 0, 0);
                acc = __builtin_amdgcn_mfma_f32_16x16x32_bf16(a3[1], bw1, acc, 0, 0, 0);
                #pragma unroll
                for (int r = 0; r < 4; ++r)
                    zw[(fq * 4 + r) * 72 + t * 16 + fr] = f2bf(acc[r]);
            }
            #pragma unroll 4
            for (int i = 0; i < 16; ++i)
                Ynext[(size_t)(base + i) * 64 + lane] = zw[i * 72 + lane];
        }
    }
}

// ---------------- final graph-level GEMM: [G,320] @ [320,16] + bc ----------------
__global__ __launch_bounds__(256) void final_gemm(
    const float* __restrict__ R, const float* __restrict__ Wc,
    const float* __restrict__ bc, float* __restrict__ out)
{
    const int tid = blockIdx.x * 256 + threadIdx.x;
    if (tid >= GG * OUTC) return;
    const int g = tid >> 4;
    const int o = tid & 15;
    float acc = bc[o];
    const float* r = R + (size_t)g * RCOLS;
    #pragma unroll 8
    for (int k = 0; k < RCOLS; ++k)
        acc += r[k] * Wc[k * OUTC + o];
    out[tid] = acc;
}

extern "C" void kernel_launch(void* const* d_in, const int* in_sizes, int n_in,
                              void* d_out, int out_size, void* d_ws, size_t ws_size,
                              hipStream_t stream)
{
    const float* x    = (const float*)d_in[0];
    const int*   ei   = (const int*)d_in[1];
    const int*   batch= (const int*)d_in[2];
    const float* eps  = (const float*)d_in[3];
    const float* W1_0 = (const float*)d_in[4];
    const float* b1_0 = (const float*)d_in[5];
    const float* W1_r = (const float*)d_in[6];
    const float* b1_r = (const float*)d_in[7];
    const float* g_a  = (const float*)d_in[8];
    const float* be_a = (const float*)d_in[9];
    const float* m_a  = (const float*)d_in[10];
    const float* v_a  = (const float*)d_in[11];
    const float* W2   = (const float*)d_in[12];
    const float* b2   = (const float*)d_in[13];
    const float* g_b  = (const float*)d_in[14];
    const float* be_b = (const float*)d_in[15];
    const float* m_b  = (const float*)d_in[16];
    const float* v_b  = (const float*)d_in[17];
    const float* Wc   = (const float*)d_in[18];
    const float* bc   = (const float*)d_in[19];
    float* out = (float*)d_out;

    const int* src = ei;
    const int* dst = ei + EE;

    // workspace layout (bytes); y buffers have NN+1 rows (row NN = zeros, gather pad target)
    char* ws = (char*)d_ws;
    int*    rowptr  = (int*)(ws);                        // (N+1)*4
    int*    bcnt    = (int*)(ws + 524288);               // NBUCK
    int*    bbase   = (int*)(ws + 528384);               // NBUCK+1
    int*    bcur    = (int*)(ws + 532480);               // NBUCK
    int*    col     = (int*)(ws + 1048576);              // E*4 = 6.4MB
    uint*   bin     = (uint*)(ws + 7602176);             // E*4 = 6.4MB
    ushort* y_a     = (ushort*)(ws + 14155776);          // (N+1)*64*2
    ushort* y_b     = (ushort*)(ws + 26955904);          // (N+1)*64*2
    float*  readout = (float*)(ws + 39756032);           // 640KB
    ushort* w2t_g   = (ushort*)(ws + 40411392);          // 5*64*72*2 = 46080
    ushort* w1nt_g  = (ushort*)(ws + 40457472);          // 4*64*72*2 = 36864

    hipMemsetAsync(bcnt, 0, (size_t)NBUCK * 4, stream);
    hipMemsetAsync(readout, 0, (size_t)GG * RCOLS * 4, stream);
    hipMemsetAsync(y_a + (size_t)NN * 64, 0, 128, stream);   // zero pad-row
    hipMemsetAsync(y_b + (size_t)NN * 64, 0, 128, stream);

    prep_w_kernel<<<80, 256, 0, stream>>>(W2, W1_r, w2t_g, w1nt_g);
    binhist_kernel<<<256, 256, 0, stream>>>(dst, bcnt);
    ingemm_kernel<<<NGRP, 256, 0, stream>>>(x, W1_0, y_a);   // y0 = x @ W1_0
    binscan_kernel<<<1, 512, 0, stream>>>(bcnt, bbase, bcur);
    binfill_kernel<<<128, 256, 0, stream>>>(src, dst, bcur, bin);
    bucket_csr_kernel<<<NBUCK, 256, 0, stream>>>(bin, bbase, rowptr, col);

    ushort* y_cur = y_a;
    ushort* y_nxt = y_b;

    for (int l = 0; l < LL; ++l) {
        const float* b1 = (l == 0) ? b1_0 : (b1_r + (size_t)(l - 1) * 64);
        const int off = l * 64;
        const ushort* w2t  = w2t_g + (size_t)l * 4608;
        const ushort* w1nt = (l < LL - 1) ? (w1nt_g + (size_t)l * 4608) : w1nt_g;
        if (l < LL - 1) {
            gin_layer_kernel<false><<<NGRP, 256, 0, stream>>>(
                y_cur, rowptr, col, eps, l, b1,
                w2t, b2 + off,
                g_a + off, be_a + off, m_a + off, v_a + off,
                g_b + off, be_b + off, m_b + off, v_b + off,
                w1nt, batch, y_nxt, readout, off);
        } else {
            gin_layer_kernel<true><<<NGRP, 256, 0, stream>>>(
                y_cur, rowptr, col, eps, l, b1,
                w2t, b2 + off,
                g_a + off, be_a + off, m_a + off, v_a + off,
                g_b + off, be_b + off, m_b + off, v_b + off,
                w1nt, batch, y_nxt, readout, off);
        }
        ushort* t = y_cur; y_cur = y_nxt; y_nxt = t;
    }

    final_gemm<<<(GG * OUTC + 255) / 256, 256, 0, stream>>>(readout, Wc, bc, out);
}

// Round 9
// 312.575 us; speedup vs baseline: 27.7708x; 1.2194x over previous
//
#include <hip/hip_runtime.h>

#define NN 100000
#define EE 1600000
#define GG 512
#define LL 5
#define HID 64
#define RCOLS (HID*LL)   // 320
#define OUTC 16
#define NGRP ((NN + 63) / 64)     // 1563
#define NBUCK ((NN + 255) / 256)  // 391 buckets of 256 nodes
#define BCAP 4864                 // bucket capacity: mean 4096 + 12 sigma

typedef unsigned int uint;
typedef unsigned short ushort;
typedef __attribute__((ext_vector_type(8))) short short8;
typedef __attribute__((ext_vector_type(4))) float f32x4;

__device__ __forceinline__ float bf2f(ushort u) {
    return __uint_as_float(((uint)u) << 16);
}
__device__ __forceinline__ ushort f2bf(float f) {
    uint u = __float_as_uint(f);
    u = (u + 0x7fffu + ((u >> 16) & 1u)) >> 16;   // round-to-nearest-even
    return (ushort)u;
}
__device__ __forceinline__ uint pack2(float a, float b) {
    return (uint)f2bf(a) | ((uint)f2bf(b) << 16);
}
__device__ __forceinline__ float lo16(uint p) { return __uint_as_float(p << 16); }
__device__ __forceinline__ float hi16(uint p) { return __uint_as_float(p & 0xffff0000u); }

// ================= bucketed CSR build, fixed-capacity buckets =================
__global__ __launch_bounds__(256) void init_bcur_kernel(int* __restrict__ bcur)
{
    int i = blockIdx.x * 256 + threadIdx.x;
    if (i < NBUCK) bcur[i] = i * BCAP;
}

// bin edges by bucket; per-block bulk reservation -> append-style writes
__global__ __launch_bounds__(256) void binfill_kernel(
    const int* __restrict__ src, const int* __restrict__ dst,
    int* __restrict__ bcur, uint* __restrict__ bin)
{
    __shared__ int hcnt[NBUCK], hbase[NBUCK];
    const int tid = threadIdx.x;
    for (int b = tid; b < NBUCK; b += 256) hcnt[b] = 0;
    __syncthreads();
    const int chunk = (EE + gridDim.x - 1) / gridDim.x;
    const int e0 = blockIdx.x * chunk;
    const int e1 = (e0 + chunk < EE) ? e0 + chunk : EE;
    for (int e = e0 + tid; e < e1; e += 256)
        atomicAdd(&hcnt[dst[e] >> 8], 1);
    __syncthreads();
    for (int b = tid; b < NBUCK; b += 256) {
        int c = hcnt[b];
        hbase[b] = c ? atomicAdd(&bcur[b], c) : 0;
        hcnt[b] = 0;
    }
    __syncthreads();
    for (int e = e0 + tid; e < e1; e += 256) {
        int d = dst[e];
        int b = d >> 8;
        int off = atomicAdd(&hcnt[b], 1);
        bin[hbase[b] + off] = ((uint)src[e] << 8) | (uint)(d & 255);   // src<2^24
    }
}

// per-bucket: LDS hist(256 nodes) -> LDS scan -> rowptr/rowend; LDS-cursor scatter -> col
__global__ __launch_bounds__(256) void bucket_csr_kernel(
    const uint* __restrict__ bin, const int* __restrict__ bcur,
    int* __restrict__ rowptr, int* __restrict__ rowend, int* __restrict__ col)
{
    __shared__ int h[256], s[256];
    const int b = blockIdx.x;
    const int tid = threadIdx.x;
    const int base = b * BCAP;
    const int cnt = bcur[b] - base;
    h[tid] = 0;
    __syncthreads();
    for (int i = tid; i < cnt; i += 256)
        atomicAdd(&h[bin[base + i] & 255], 1);
    __syncthreads();
    const int own = h[tid];
    s[tid] = own;
    __syncthreads();
    int val = own;
    for (int off = 1; off < 256; off <<= 1) {
        int other = (tid >= off) ? s[tid - off] : 0;
        __syncthreads();
        val += other;
        s[tid] = val;
        __syncthreads();
    }
    const int excl = val - own;
    const int node = b * 256 + tid;
    if (node < NN) {
        rowptr[node] = base + excl;
        rowend[node] = base + excl + own;
    }
    h[tid] = base + excl;      // per-node cursor
    __syncthreads();
    for (int i = tid; i < cnt; i += 256) {
        uint w = bin[base + i];
        int p = atomicAdd(&h[w & 255], 1);
        col[p] = (int)(w >> 8);
    }
}

// -------- prep: transposed bf16 weights, [c][72] padded rows, L1-resident at use --------
__global__ __launch_bounds__(256) void prep_w_kernel(
    const float* __restrict__ W2, const float* __restrict__ W1_r,
    ushort* __restrict__ w2t, ushort* __restrict__ w1nt)
{
    const int i = blockIdx.x * 256 + threadIdx.x;
    if (i < 5 * 4096) {
        int l = i >> 12, r = i & 4095, k = r >> 6, c = r & 63;
        w2t[l * 4608 + c * 72 + k] = f2bf(W2[l * 4096 + k * 64 + c]);
    }
    if (i < 4 * 4096) {
        int l = i >> 12, r = i & 4095, k = r >> 6, c = r & 63;
        w1nt[l * 4608 + c * 72 + k] = f2bf(W1_r[l * 4096 + k * 64 + c]);
    }
}

// ---------------- y0 = x @ W1_0  (fp32 [N,128] @ [128,64] -> bf16 [N,64]) ----------------
// mfma(A-frag,B-frag) = A·B^T, frags k-contiguous per lane; C/D col=lane&15, row=(lane>>4)*4+r.
__global__ __launch_bounds__(256) void ingemm_kernel(
    const float* __restrict__ x, const float* __restrict__ W1,
    ushort* __restrict__ Y0)
{
    __shared__ __align__(16) ushort W1t[64 * 136];   // W1^T [c][k], k=0..127, pad 136
    __shared__ __align__(16) ushort zA[4][16 * 72];

    for (int e = threadIdx.x; e < 64 * 128; e += 256) {
        int c = e & 63, k = e >> 6;
        W1t[c * 136 + k] = f2bf(W1[k * 64 + c]);
    }
    __syncthreads();

    const int lane = threadIdx.x & 63;
    const int wave = threadIdx.x >> 6;
    const int fr = lane & 15, fq = lane >> 4;
    ushort* zw = zA[wave];

    for (int grp = blockIdx.x; grp < NGRP; grp += gridDim.x) {
        const int base = grp * 64 + wave * 16;
        if (base >= NN) continue;

        short8 az[4];
        #pragma unroll
        for (int h = 0; h < 4; ++h) {
            const float* xp = x + (size_t)(base + fr) * 128 + h * 32 + fq * 8;
            float4 f0 = *(const float4*)xp;
            float4 f1 = *(const float4*)(xp + 4);
            short8 a;
            a[0] = (short)f2bf(f0.x); a[1] = (short)f2bf(f0.y);
            a[2] = (short)f2bf(f0.z); a[3] = (short)f2bf(f0.w);
            a[4] = (short)f2bf(f1.x); a[5] = (short)f2bf(f1.y);
            a[6] = (short)f2bf(f1.z); a[7] = (short)f2bf(f1.w);
            az[h] = a;
        }
        #pragma unroll
        for (int t = 0; t < 4; ++t) {
            f32x4 acc = {0.f, 0.f, 0.f, 0.f};
            #pragma unroll
            for (int h = 0; h < 4; ++h) {
                short8 bw = *(const short8*)&W1t[(t * 16 + fr) * 136 + h * 32 + fq * 8];
                acc = __builtin_amdgcn_mfma_f32_16x16x32_bf16(az[h], bw, acc, 0, 0, 0);
            }
            #pragma unroll
            for (int r = 0; r < 4; ++r)
                zw[(fq * 4 + r) * 72 + t * 16 + fr] = f2bf(acc[r]);
        }
        #pragma unroll 4
        for (int i = 0; i < 16; ++i)
            Y0[(size_t)(base + i) * 64 + lane] = zw[i * 72 + lane];
    }
}

// ------- fused layer on Y = h@W1 (bf16 [NN+1,64], row NN == zeros):
//   gather t = (1+eps)*Y[row] + sum Y[neigh]   (linear-commute: this IS z@W1)
//   v1 = relu(t*sa+sh); v2 = relu((v1@W2)*sb+shb); pool; Ynext = v2 @ W1next
// Gather: uint2 (8B) loads; 2 dst rows x 2 neighbor-slots x 16 lanes per instr
// (512 B / 4 neighbor-rows per load). Slot combine = one shfl_xor(16).
// Index pads -> row NN (zero, cache-resident) => branch-free unrolled loads.
template<bool LAST>
__global__ __launch_bounds__(256, 7) void gin_layer_kernel(
    const ushort* __restrict__ Y,
    const int* __restrict__ rowptr, const int* __restrict__ rowend,
    const int* __restrict__ col,
    const float* __restrict__ eps_arr, int l,
    const float* __restrict__ b1,
    const ushort* __restrict__ w2t,    // bf16 [64][72] W2^T
    const float* __restrict__ b2,
    const float* __restrict__ g_a, const float* __restrict__ be_a,
    const float* __restrict__ m_a, const float* __restrict__ v_a,
    const float* __restrict__ g_b, const float* __restrict__ be_b,
    const float* __restrict__ m_b, const float* __restrict__ v_b,
    const ushort* __restrict__ w1nt,   // bf16 [64][72] W1next^T (unused if LAST)
    const int* __restrict__ batch,
    ushort* __restrict__ Ynext,
    float* __restrict__ readout,
    int layer_off)
{
    __shared__ __align__(16) ushort zA[4][16 * 72];   // per-wave tile [r][k]
    __shared__ float2 bnA[64], bnB[64];
    __shared__ __align__(16) int idxs[4][144];        // [72 rowA | 72 rowB], pads=NN

    if (threadIdx.x < 64) {
        int c = threadIdx.x;
        float sa = g_a[c] * rsqrtf(v_a[c] + 1e-5f);
        float sb = g_b[c] * rsqrtf(v_b[c] + 1e-5f);
        bnA[c] = make_float2(sa, be_a[c] + (b1[c] - m_a[c]) * sa);
        bnB[c] = make_float2(sb, be_b[c] + (b2[c] - m_b[c]) * sb);
    }
    const float eps_l = 1.0f + eps_arr[l];
    __syncthreads();

    const int lane = threadIdx.x & 63;
    const int wave = threadIdx.x >> 6;
    const int fr = lane & 15, fq = lane >> 4;
    const int c4 = (lane & 15) * 4;        // channel base (4 channels per lane)
    const int sl = (lane >> 4) & 1;        // neighbor slot within half
    const int rb = (lane >> 5) * 72;       // idw base: 0=row A half, 72=row B half
    ushort* zw = zA[wave];
    int* idw = idxs[wave];
    const float2 ba0 = bnA[c4], ba1 = bnA[c4 + 1], ba2 = bnA[c4 + 2], ba3 = bnA[c4 + 3];

    for (int grp = blockIdx.x; grp < NGRP; grp += gridDim.x) {
        const int base = grp * 64 + wave * 16;
        if (base >= NN) continue;      // NN%16==0: waves all-valid or all-idle

        // ---- phase 1: gather pairs of rows; 4 uint2 loads (16 neighbor-rows) in flight ----
        for (int i = 0; i < 16; i += 2) {
            const int rowA = base + i, rowB = base + i + 1;
            int ja = rowptr[rowA];
            const int reA = rowend[rowA];
            int jb = reA;                       // rowB contiguous after rowA (same bucket)
            const int reB = rowend[rowB];
            float a0 = 0.f, a1 = 0.f, a2 = 0.f, a3 = 0.f;
            while (ja < reA || jb < reB) {
                int cntA = reA - ja; cntA = cntA > 64 ? 64 : cntA;
                int cntB = reB - jb; cntB = cntB > 64 ? 64 : cntB;
                {
                    int ia = ja + (lane < cntA ? lane : 0);
                    int ca = col[ia];
                    idw[lane] = (lane < cntA) ? ca : NN;
                    int ib = jb + (lane < cntB ? lane : 0);
                    int cb = col[ib];
                    idw[72 + lane] = (lane < cntB) ? cb : NN;
                    if (lane < 8) { idw[64 + lane] = NN; idw[136 + lane] = NN; }
                }
                const int niA = (cntA + 1) >> 1, niB = (cntB + 1) >> 1;
                const int ni = niA > niB ? niA : niB;
                for (int t = 0; t < ni; t += 4) {
                    int r0 = idw[rb + (t + 0) * 2 + sl];
                    int r1 = idw[rb + (t + 1) * 2 + sl];
                    int r2 = idw[rb + (t + 2) * 2 + sl];
                    int r3 = idw[rb + (t + 3) * 2 + sl];
                    uint2 w0 = *(const uint2*)&Y[(size_t)r0 * 64 + c4];
                    uint2 w1 = *(const uint2*)&Y[(size_t)r1 * 64 + c4];
                    uint2 w2 = *(const uint2*)&Y[(size_t)r2 * 64 + c4];
                    uint2 w3 = *(const uint2*)&Y[(size_t)r3 * 64 + c4];
                    a0 += (lo16(w0.x) + lo16(w1.x)) + (lo16(w2.x) + lo16(w3.x));
                    a1 += (hi16(w0.x) + hi16(w1.x)) + (hi16(w2.x) + hi16(w3.x));
                    a2 += (lo16(w0.y) + lo16(w1.y)) + (lo16(w2.y) + lo16(w3.y));
                    a3 += (hi16(w0.y) + hi16(w1.y)) + (hi16(w2.y) + hi16(w3.y));
                }
                ja += cntA; jb += cntB;
            }
            // combine the two neighbor-slots within each half
            a0 += __shfl_xor(a0, 16); a1 += __shfl_xor(a1, 16);
            a2 += __shfl_xor(a2, 16); a3 += __shfl_xor(a3, 16);
            // self row + BN + ReLU
            const int myrow = (lane < 32) ? rowA : rowB;
            uint2 wr = *(const uint2*)&Y[(size_t)myrow * 64 + c4];
            a0 += eps_l * lo16(wr.x); a1 += eps_l * hi16(wr.x);
            a2 += eps_l * lo16(wr.y); a3 += eps_l * hi16(wr.y);
            float z0 = fmaxf(a0 * ba0.x + ba0.y, 0.f);
            float z1 = fmaxf(a1 * ba1.x + ba1.y, 0.f);
            float z2 = fmaxf(a2 * ba2.x + ba2.y, 0.f);
            float z3 = fmaxf(a3 * ba3.x + ba3.y, 0.f);
            if ((lane & 31) < 16) {    // lanes 0-15 write rowA, 32-47 write rowB
                uint2 pz;
                pz.x = pack2(z0, z1);
                pz.y = pack2(z2, z3);
                *(uint2*)&zw[(i + (lane >> 5)) * 72 + c4] = pz;
            }
        }

        // ---- phase 2: v2 = relu(bnB(v1 @ W2)) -> zw (B-frags from L1-resident global) ----
        short8 a2f[2];
        a2f[0] = *(const short8*)&zw[fr * 72 + fq * 8];
        a2f[1] = *(const short8*)&zw[fr * 72 + 32 + fq * 8];
        #pragma unroll
        for (int t = 0; t < 4; ++t) {
            f32x4 acc = {0.f, 0.f, 0.f, 0.f};
            short8 bw0 = *(const short8*)&w2t[(t * 16 + fr) * 72 + fq * 8];
            short8 bw1 = *(const short8*)&w2t[(t * 16 + fr) * 72 + 32 + fq * 8];
            acc = __builtin_amdgcn_mfma_f32_16x16x32_bf16(a2f[0], bw0, acc, 0, 0, 0);
            acc = __builtin_amdgcn_mfma_f32_16x16x32_bf16(a2f[1], bw1, acc, 0, 0, 0);
            float2 bn = bnB[t * 16 + fr];
            #pragma unroll
            for (int r = 0; r < 4; ++r) {
                float v = fmaxf(acc[r] * bn.x + bn.y, 0.f);
                zw[(fq * 4 + r) * 72 + t * 16 + fr] = f2bf(v);
            }
        }

        // ---- phase 3: run-length-reduced readout atomics ----
        {
            int curg = batch[base];
            float racc = 0.f;
            #pragma unroll 4
            for (int i = 0; i < 16; ++i) {
                const float v = bf2f(zw[i * 72 + lane]);
                const int g = batch[base + i];
                if (g != curg) {   // wave-uniform (batch sorted)
                    unsafeAtomicAdd(readout + (size_t)curg * RCOLS + layer_off + lane, racc);
                    curg = g;
                    racc = v;
                } else {
                    racc += v;
                }
            }
            unsafeAtomicAdd(readout + (size_t)curg * RCOLS + layer_off + lane, racc);
        }

        // ---- phase 4: Ynext = v2 @ W1next; coalesced row stores ----
        if constexpr (!LAST) {
            short8 a3f[2];
            a3f[0] = *(const short8*)&zw[fr * 72 + fq * 8];
            a3f[1] = *(const short8*)&zw[fr * 72 + 32 + fq * 8];
            #pragma unroll
            for (int t = 0; t < 4; ++t) {
                f32x4 acc = {0.f, 0.f, 0.f, 0.f};
                short8 bw0 = *(const short8*)&w1nt[(t * 16 + fr) * 72 + fq * 8];
                short8 bw1 = *(const short8*)&w1nt[(t * 16 + fr) * 72 + 32 + fq * 8];
                acc = __builtin_amdgcn_mfma_f32_16x16x32_bf16(a3f[0], bw0, acc, 0, 0, 0);
                acc = __builtin_amdgcn_mfma_f32_16x16x32_bf16(a3f[1], bw1, acc, 0, 0, 0);
                #pragma unroll
                for (int r = 0; r < 4; ++r)
                    zw[(fq * 4 + r) * 72 + t * 16 + fr] = f2bf(acc[r]);
            }
            #pragma unroll 4
            for (int i = 0; i < 16; ++i)
                Ynext[(size_t)(base + i) * 64 + lane] = zw[i * 72 + lane];
        }
    }
}

// ---------------- final graph-level GEMM: [G,320] @ [320,16] + bc ----------------
__global__ __launch_bounds__(256) void final_gemm(
    const float* __restrict__ R, const float* __restrict__ Wc,
    const float* __restrict__ bc, float* __restrict__ out)
{
    const int tid = blockIdx.x * 256 + threadIdx.x;
    if (tid >= GG * OUTC) return;
    const int g = tid >> 4;
    const int o = tid & 15;
    float acc = bc[o];
    const float* r = R + (size_t)g * RCOLS;
    #pragma unroll 8
    for (int k = 0; k < RCOLS; ++k)
        acc += r[k] * Wc[k * OUTC + o];
    out[tid] = acc;
}

extern "C" void kernel_launch(void* const* d_in, const int* in_sizes, int n_in,
                              void* d_out, int out_size, void* d_ws, size_t ws_size,
                              hipStream_t stream)
{
    const float* x    = (const float*)d_in[0];
    const int*   ei   = (const int*)d_in[1];
    const int*   batch= (const int*)d_in[2];
    const float* eps  = (const float*)d_in[3];
    const float* W1_0 = (const float*)d_in[4];
    const float* b1_0 = (const float*)d_in[5];
    const float* W1_r = (const float*)d_in[6];
    const float* b1_r = (const float*)d_in[7];
    const float* g_a  = (const float*)d_in[8];
    const float* be_a = (const float*)d_in[9];
    const float* m_a  = (const float*)d_in[10];
    const float* v_a  = (const float*)d_in[11];
    const float* W2   = (const float*)d_in[12];
    const float* b2   = (const float*)d_in[13];
    const float* g_b  = (const float*)d_in[14];
    const float* be_b = (const float*)d_in[15];
    const float* m_b  = (const float*)d_in[16];
    const float* v_b  = (const float*)d_in[17];
    const float* Wc   = (const float*)d_in[18];
    const float* bc   = (const float*)d_in[19];
    float* out = (float*)d_out;

    const int* src = ei;
    const int* dst = ei + EE;

    // workspace layout (bytes); y buffers have NN+1 rows (row NN = zeros, gather pad target)
    char* ws = (char*)d_ws;
    int*    rowptr  = (int*)(ws);                        // N*4
    int*    rowend  = (int*)(ws + 524288);               // N*4
    int*    bcur    = (int*)(ws + 1048576);              // NBUCK*4
    int*    col     = (int*)(ws + 1572864);              // NBUCK*BCAP*4 (+slack)
    uint*   bin     = (uint*)(ws + 9437184);             // NBUCK*BCAP*4
    ushort* y_a     = (ushort*)(ws + 17301504);          // (N+1)*64*2
    ushort* y_b     = (ushort*)(ws + 30212096);          // (N+1)*64*2
    float*  readout = (float*)(ws + 43122688);           // 640KB
    ushort* w2t_g   = (ushort*)(ws + 43778048);          // 5*64*72*2
    ushort* w1nt_g  = (ushort*)(ws + 43824128);          // 4*64*72*2

    hipMemsetAsync(readout, 0, (size_t)GG * RCOLS * 4, stream);
    hipMemsetAsync(y_a + (size_t)NN * 64, 0, 128, stream);   // zero pad-row
    hipMemsetAsync(y_b + (size_t)NN * 64, 0, 128, stream);

    init_bcur_kernel<<<(NBUCK + 255) / 256, 256, 0, stream>>>(bcur);
    prep_w_kernel<<<80, 256, 0, stream>>>(W2, W1_r, w2t_g, w1nt_g);
    ingemm_kernel<<<NGRP, 256, 0, stream>>>(x, W1_0, y_a);   // y0 = x @ W1_0
    binfill_kernel<<<256, 256, 0, stream>>>(src, dst, bcur, bin);
    bucket_csr_kernel<<<NBUCK, 256, 0, stream>>>(bin, bcur, rowptr, rowend, col);

    ushort* y_cur = y_a;
    ushort* y_nxt = y_b;

    for (int l = 0; l < LL; ++l) {
        const float* b1 = (l == 0) ? b1_0 : (b1_r + (size_t)(l - 1) * 64);
        const int off = l * 64;
        const ushort* w2t  = w2t_g + (size_t)l * 4608;
        const ushort* w1nt = (l < LL - 1) ? (w1nt_g + (size_t)l * 4608) : w1nt_g;
        if (l < LL - 1) {
            gin_layer_kernel<false><<<NGRP, 256, 0, stream>>>(
                y_cur, rowptr, rowend, col, eps, l, b1,
                w2t, b2 + off,
                g_a + off, be_a + off, m_a + off, v_a + off,
                g_b + off, be_b + off, m_b + off, v_b + off,
                w1nt, batch, y_nxt, readout, off);
        } else {
            gin_layer_kernel<true><<<NGRP, 256, 0, stream>>>(
                y_cur, rowptr, rowend, col, eps, l, b1,
                w2t, b2 + off,
                g_a + off, be_a + off, m_a + off, v_a + off,
                g_b + off, be_b + off, m_b + off, v_b + off,
                w1nt, batch, y_nxt, readout, off);
        }
        ushort* t = y_cur; y_cur = y_nxt; y_nxt = t;
    }

    final_gemm<<<(GG * OUTC + 255) / 256, 256, 0, stream>>>(readout, Wc, bc, out);
}